// Round 3
// baseline (1207.050 us; speedup 1.0000x reference)
//
#include <hip/hip_runtime.h>
#include <math.h>

#define NN 6144
#define FIN 256
#define HID 64
#define NW 96  // NN/64 bitmask words per row
typedef unsigned long long u64;

// All inputs and outputs are float32 (reference dtypes). d_out is float*.

// ---------- hxw = x @ W1 (fp64 accumulate; feeds decision-critical chain) ----------
__global__ __launch_bounds__(256) void k_hxw(const float* __restrict__ x,
                                             const float* __restrict__ W1,
                                             double* __restrict__ hxw) {
  int t = blockIdx.x * 256 + threadIdx.x;   // exactly N*64 threads
  int i = t >> 6, c = t & 63;
  const float* xr = x + (size_t)i * FIN;
  double a = 0.0;
#pragma unroll 8
  for (int k = 0; k < FIN; ++k)
    a = fma((double)xr[k], (double)W1[k * HID + c], a);
  hxw[t] = a;
}

// ---------- degree count + adj_orig bitmask scatter (float adjO written by k_tile) ----------
__global__ __launch_bounds__(256) void k_edges(const int* __restrict__ ei, int E,
                                               int* __restrict__ deg,
                                               u64* __restrict__ bitO) {
  int e = blockIdx.x * 256 + threadIdx.x;
  if (e >= E) return;
  int s = ei[e], d = ei[E + e];
  atomicAdd(&deg[d], 1);
  atomicOr(&bitO[(size_t)s * NW + (d >> 6)], 1ull << (d & 63));
}

__global__ __launch_bounds__(256) void k_dinv(const int* __restrict__ deg,
                                              double* __restrict__ dinv) {
  int i = blockIdx.x * 256 + threadIdx.x;
  if (i < NN) dinv[i] = 1.0 / sqrt((double)(deg[i] + 1));  // +1: self-loop
}

// ---------- GCN edge aggregation (fp64 atomics) ----------
__global__ __launch_bounds__(256) void k_agg(const int* __restrict__ ei, int E,
                                             const double* __restrict__ hxw,
                                             const double* __restrict__ dinv,
                                             double* __restrict__ hagg) {
  int t = blockIdx.x * 256 + threadIdx.x;
  if (t >= E * HID) return;
  int e = t >> 6, c = t & 63;
  int s = ei[e], d = ei[E + e];
  atomicAdd(&hagg[(size_t)d * HID + c], hxw[(size_t)s * HID + c] * (dinv[s] * dinv[d]));
}

// ---------- fused: self-loop term + bias, then Lmax row-norm (one row per thread) ----------
// Expression shapes copied verbatim from the previous k_selfbias / k_lmax so codegen
// (fma contraction) and the sequential c-ascending norm chain stay identical ->
// hagg values and Lmax bitwise unchanged.
__global__ __launch_bounds__(256) void k_sblmax(const double* __restrict__ hxw,
                                                const double* __restrict__ dinv,
                                                const float* __restrict__ b1,
                                                double* __restrict__ hagg,
                                                u64* __restrict__ lmax) {
  __shared__ double red[256];
  int i = blockIdx.x * 256 + threadIdx.x;
  double di = dinv[i];
  double* hr = hagg + (size_t)i * HID;
  const double* xr = hxw + (size_t)i * HID;
  double s = 0.0;
  for (int c = 0; c < HID; ++c) {
    double v = hr[c] + (xr[c] * di * di + (double)b1[c]);
    hr[c] = v;
    s = fma(v, v, s);
  }
  red[threadIdx.x] = s;
  __syncthreads();
  for (int w = 128; w > 0; w >>= 1) {
    if (threadIdx.x < w) {
      double o = red[threadIdx.x + w];
      if (o > red[threadIdx.x]) red[threadIdx.x] = o;
    }
    __syncthreads();
  }
  if (threadIdx.x == 0)
    atomicMax(lmax, (u64)__double_as_longlong(red[0]));  // vals > 0: bits monotone
}

// 16 fp64 fmas for one k-substep; a?s are scalars (rows ty+16p), cv?s are scalars (cols tx+16q).
#define FMA16D(A0, A1, A2, A3, C0, C1, C2, C3)                                   \
  acc[0][0] = fma(A0, C0, acc[0][0]); acc[0][1] = fma(A0, C1, acc[0][1]);        \
  acc[0][2] = fma(A0, C2, acc[0][2]); acc[0][3] = fma(A0, C3, acc[0][3]);        \
  acc[1][0] = fma(A1, C0, acc[1][0]); acc[1][1] = fma(A1, C1, acc[1][1]);        \
  acc[1][2] = fma(A1, C2, acc[1][2]); acc[1][3] = fma(A1, C3, acc[1][3]);        \
  acc[2][0] = fma(A2, C0, acc[2][0]); acc[2][1] = fma(A2, C1, acc[2][1]);        \
  acc[2][2] = fma(A2, C2, acc[2][2]); acc[2][3] = fma(A2, C3, acc[2][3]);        \
  acc[3][0] = fma(A3, C0, acc[3][0]); acc[3][1] = fma(A3, C1, acc[3][1]);        \
  acc[3][2] = fma(A3, C2, acc[3][2]); acc[3][3] = fma(A3, C3, acc[3][3]);

// ---------- big fused N^2 kernel: L = h h^T tile, adj_logits + straight-through sample ----------
// round(sigmoid(logit(p)+logit(u))) == (p > 1-u): logit strictly monotone, tie -> 0 (round-half-even).
// Grid (96,96); blocks with J<I exit; block (I,J), I<J also writes mirrored (J,I) tiles via LDS transpose.
// adjO (float) is expanded from bitO here. adjS bits go to bitT in TRANSPOSED [Jblock][row] layout.
__global__ __launch_bounds__(256) void k_tile(const double* __restrict__ h,
                                              const u64* __restrict__ lmaxp,
                                              const float* __restrict__ u,
                                              const u64* __restrict__ bitO,
                                              float* __restrict__ adjL,
                                              float* __restrict__ adjS,
                                              float* __restrict__ adjO,
                                              u64* __restrict__ bitT) {
  int I = blockIdx.y, J = blockIdx.x;
  if (J < I) return;
  __shared__ __align__(16) double smem[2 * 64 * 34];  // 34,816 B
  double* As = smem;                                  // 64x34
  double* Bs = smem + 64 * 34;
  float* Ls = (float*)smem;                           // 64x68 f32 (17,408 B), aliases As
  float* Ss = ((float*)smem) + 64 * 68;               // 64x68 f32, aliases Bs
  int t = threadIdx.x;
  int tx = t & 15, ty = t >> 4;
  double acc[4][4];
#pragma unroll
  for (int p = 0; p < 4; ++p)
#pragma unroll
    for (int q = 0; q < 4; ++q) acc[p][q] = 0.0;
  const double* hI = h + (size_t)I * 64 * HID;
  const double* hJ = h + (size_t)J * 64 * HID;
  for (int k0 = 0; k0 < 64; k0 += 32) {
    __syncthreads();
    for (int idx = t; idx < 1024; idx += 256) {
      int r = idx >> 4, k2 = (idx & 15) << 1;
      *(double2*)&As[r * 34 + k2] = *(const double2*)&hI[r * 64 + k0 + k2];
      *(double2*)&Bs[r * 34 + k2] = *(const double2*)&hJ[r * 64 + k0 + k2];
    }
    __syncthreads();
#pragma unroll 8
    for (int k = 0; k < 32; k += 2) {
      double2 A0 = *(const double2*)&As[ty * 34 + k];
      double2 A1 = *(const double2*)&As[(ty + 16) * 34 + k];
      double2 A2 = *(const double2*)&As[(ty + 32) * 34 + k];
      double2 A3 = *(const double2*)&As[(ty + 48) * 34 + k];
      double2 C0 = *(const double2*)&Bs[tx * 34 + k];
      double2 C1 = *(const double2*)&Bs[(tx + 16) * 34 + k];
      double2 C2 = *(const double2*)&Bs[(tx + 32) * 34 + k];
      double2 C3 = *(const double2*)&Bs[(tx + 48) * 34 + k];
      FMA16D(A0.x, A1.x, A2.x, A3.x, C0.x, C1.x, C2.x, C3.x)  // k
      FMA16D(A0.y, A1.y, A2.y, A3.y, C0.y, C1.y, C2.y, C3.y)  // k+1
    }
  }
  __syncthreads();  // As/Bs dead from here; Ls/Ss may overwrite
  double Lmax = __longlong_as_double((long long)(*lmaxp));
  bool diag = (I == J);
#pragma unroll
  for (int p = 0; p < 4; ++p) {
    int r = ty + 16 * p;
    int gi = I * 64 + r;
    u64 wO = bitO[(size_t)gi * NW + J];  // directed bits, row gi, col-block J
    float sv[4];
#pragma unroll
    for (int q = 0; q < 4; ++q) {
      int c = tx + 16 * q;
      int gj = J * 64 + c;
      double L = acc[p][q];
      float lf = (float)L;
      adjL[(size_t)gi * NN + gj] = lf;
      adjO[(size_t)gi * NN + gj] = (float)((wO >> c) & 1ull);
      float stv;
      if (diag && r == c) {
        stv = 1.0f;  // fill_diagonal_(1)
      } else {
        // only the upper-triangle (a<b) entry decides; L[a,b]==L[b,a] bitwise
        int ga = gi < gj ? gi : gj, gb = gi < gj ? gj : gi;
        size_t ab = (size_t)ga * NN + gb;
        double uu = (double)u[ab];
        double ao = (double)(int)((bitO[(size_t)ga * NW + (gb >> 6)] >> (gb & 63)) & 1ull);
        double ep = 0.8 * (L / Lmax) + 0.2 * ao;
        if (ep < 0.0) ep = 0.0;
        double pl = ep;
        if (pl < 1e-6) pl = 1e-6;
        double hi = 1.0 - 1e-6;
        if (pl > hi) pl = hi;
        stv = (pl > 1.0 - uu) ? 1.0f : 0.0f;  // == round(sigmoid(logit(pl)+logit(uu)))
      }
      sv[q] = stv;
      adjS[(size_t)gi * NN + gj] = stv;
      if (!diag) {
        Ls[c * 68 + r] = lf;   // store transposed for mirror tile
        Ss[c * 68 + r] = stv;
      }
    }
    // pack this row's 64 sample bits: wave lane l = (ty&3)*16+tx holds (row ty+16p, col tx+16q)
    u64 word = 0;
#pragma unroll
    for (int q = 0; q < 4; ++q) {
      u64 m = __ballot(sv[q] > 0.5f);
      word |= ((m >> ((ty & 3) * 16)) & 0xFFFFull) << (16 * q);
    }
    if (tx == 0) bitT[(size_t)J * NN + gi] = word;  // transposed: [col-block][row]
  }
  if (!diag) {
    __syncthreads();
    // mirror float tiles, float4-vectorized (stride 68*4 B = 272 -> 16B aligned rows)
    for (int i4 = t; i4 < 1024; i4 += 256) {
      int a = i4 >> 4, b4 = (i4 & 15) << 2;
      int grow = J * 64 + a;
      size_t off = (size_t)grow * NN + (I * 64 + b4);
      *(float4*)(adjL + off) = *(const float4*)&Ls[a * 68 + b4];
      *(float4*)(adjS + off) = *(const float4*)&Ss[a * 68 + b4];
      u64 wOm = bitO[(size_t)grow * NW + I];  // directed bits row grow, col-block I
      *(float4*)(adjO + off) = make_float4((float)((wOm >> b4) & 1ull),
                                           (float)((wOm >> (b4 + 1)) & 1ull),
                                           (float)((wOm >> (b4 + 2)) & 1ull),
                                           (float)((wOm >> (b4 + 3)) & 1ull));
    }
    // mirror bits: per wave-iteration all 64 lanes hold one row (a = 4*k2 + wave), col = lane
    for (int k2 = 0; k2 < 16; ++k2) {
      int idx = t + (k2 << 8);
      int a = idx >> 6, b = idx & 63;
      u64 m = __ballot(Ss[a * 68 + b] > 0.5f);
      if ((t & 63) == 0) bitT[(size_t)I * NN + (J * 64 + a)] = m;
    }
  }
}

// ---------- fused: popcount row sums -> dinv2, then g = dinv2 * hxw (same row) ----------
// Same expressions as the old k_rowsumB / k_gscale -> bitwise-identical dinv2 and g.
__global__ __launch_bounds__(256) void k_rsg(const u64* __restrict__ bitT,
                                             const double* __restrict__ hv,
                                             double* __restrict__ dinv2,
                                             float* __restrict__ g) {
  int i = blockIdx.x * 256 + threadIdx.x;
  int cnt = 0;
#pragma unroll
  for (int J = 0; J < NW; ++J) cnt += __popcll(bitT[(size_t)J * NN + i]);
  double di = 1.0 / sqrt((double)(cnt + 1));
  dinv2[i] = di;
  const double* hr = hv + (size_t)i * HID;
  float* gr = g + (size_t)i * HID;
  for (int c = 0; c < HID; ++c) gr[c] = (float)(di * hr[c]);
}

// 16 fp32 fmas for one j-substep (A? scalar per row, CV float4 per 4 cols).
#define FMA16F(A0, A1, A2, A3, CV)                                                   \
  acc[0][0] = fmaf(A0, CV.x, acc[0][0]); acc[0][1] = fmaf(A0, CV.y, acc[0][1]);      \
  acc[0][2] = fmaf(A0, CV.z, acc[0][2]); acc[0][3] = fmaf(A0, CV.w, acc[0][3]);      \
  acc[1][0] = fmaf(A1, CV.x, acc[1][0]); acc[1][1] = fmaf(A1, CV.y, acc[1][1]);      \
  acc[1][2] = fmaf(A1, CV.z, acc[1][2]); acc[1][3] = fmaf(A1, CV.w, acc[1][3]);      \
  acc[2][0] = fmaf(A2, CV.x, acc[2][0]); acc[2][1] = fmaf(A2, CV.y, acc[2][1]);      \
  acc[2][2] = fmaf(A2, CV.z, acc[2][2]); acc[2][3] = fmaf(A2, CV.w, acc[2][3]);      \
  acc[3][0] = fmaf(A3, CV.x, acc[3][0]); acc[3][1] = fmaf(A3, CV.y, acc[3][1]);      \
  acc[3][2] = fmaf(A3, CV.z, acc[3][2]); acc[3][3] = fmaf(A3, CV.w, acc[3][3]);

// ---------- dense An-matmul partial, bit-direct: slice s sums j in [s*768, (s+1)*768) ----------
// A-operand bits live in 4 registers per thread (16-lane-broadcast L2 loads of bitT); the
// float values (float)((w>>j)&1) and the per-element fma order (j asc, Jt asc, same split-K)
// are bitwise identical to the old LDS-expanded as[] path. No as[] tile: LDS holds only gs.
__global__ __launch_bounds__(256) void k_anmm(const u64* __restrict__ bitT,
                                              const float* __restrict__ g,
                                              float* __restrict__ accb) {
  int I = blockIdx.x;  // 0..95 row block
  int s = blockIdx.y;  // 0..7 split-K slice
  __shared__ __align__(16) float gs[64 * 64];  // 16,384 B
  int t = threadIdx.x, tx = t & 15, ty = t >> 4;
  float acc[4][4];
#pragma unroll
  for (int p = 0; p < 4; ++p)
#pragma unroll
    for (int q = 0; q < 4; ++q) acc[p][q] = 0.0f;
  for (int Jt = s * 12; Jt < (s + 1) * 12; ++Jt) {
    __syncthreads();
    for (int i4 = t; i4 < 1024; i4 += 256) {
      int r = i4 >> 4, c4 = (i4 & 15) << 2;
      *(float4*)&gs[r * 64 + c4] = *(const float4*)&g[(size_t)(Jt * 64 + r) * HID + c4];
    }
    const u64* bw = bitT + (size_t)Jt * NN + I * 64;
    u64 w0 = bw[ty];        // 16 lanes share each word: broadcast load, L2-resident
    u64 w1 = bw[ty + 16];
    u64 w2 = bw[ty + 32];
    u64 w3 = bw[ty + 48];
    __syncthreads();
#pragma unroll 8
    for (int j = 0; j < 64; ++j) {
      float4 cv = *(const float4*)&gs[j * 64 + (tx << 2)];
      float b0 = (float)((w0 >> j) & 1ull);
      float b1 = (float)((w1 >> j) & 1ull);
      float b2 = (float)((w2 >> j) & 1ull);
      float b3 = (float)((w3 >> j) & 1ull);
      FMA16F(b0, b1, b2, b3, cv)
    }
  }
  float* out = accb + (size_t)s * NN * HID;
#pragma unroll
  for (int p = 0; p < 4; ++p) {
    float4 v = make_float4(acc[p][0], acc[p][1], acc[p][2], acc[p][3]);
    *(float4*)&out[(size_t)(I * 64 + ty + 16 * p) * HID + (tx << 2)] = v;
  }
}

// ---------- epilogue 1: x1 = dinv2_i*(sum + g_i) + b1; z = PReLU(x1) ----------
__global__ __launch_bounds__(256) void k_ep1(const float* __restrict__ accb,
                                             const float* __restrict__ g,
                                             const double* __restrict__ dinv2,
                                             const float* __restrict__ b1,
                                             const float* __restrict__ prelu,
                                             float* __restrict__ x1,
                                             float* __restrict__ zout) {
  int t = blockIdx.x * 256 + threadIdx.x;
  int i = t >> 6, c = t & 63;
  double ss = 0.0;
  for (int s = 0; s < 8; ++s) ss += (double)accb[(size_t)s * NN * HID + t];
  float v = (float)(dinv2[i] * (ss + (double)g[t])) + b1[c];
  x1[t] = v;
  float pa = prelu[0];
  zout[t] = v >= 0.0f ? v : pa * v;
}

// ---------- BN stats (biased var, training mode) ----------
__global__ __launch_bounds__(256) void k_bnstats(const float* __restrict__ x1,
                                                 double* __restrict__ meanv,
                                                 double* __restrict__ istd) {
  __shared__ double r1[256], r2[256];
  int c = blockIdx.x;
  double s1 = 0.0, s2 = 0.0;
  for (int i = threadIdx.x; i < NN; i += 256) {
    double v = (double)x1[(size_t)i * HID + c];
    s1 += v;
    s2 += v * v;
  }
  r1[threadIdx.x] = s1;
  r2[threadIdx.x] = s2;
  __syncthreads();
  for (int w = 128; w > 0; w >>= 1) {
    if (threadIdx.x < w) {
      r1[threadIdx.x] += r1[threadIdx.x + w];
      r2[threadIdx.x] += r2[threadIdx.x + w];
    }
    __syncthreads();
  }
  if (threadIdx.x == 0) {
    double m = r1[0] / (double)NN;
    double var = r2[0] / (double)NN - m * m;
    meanv[c] = m;
    istd[c] = 1.0 / sqrt(var + 1e-5);
  }
}

// ---------- fused BN-apply + ReLU + (xr @ W2) + dinv2 scale ----------
__global__ __launch_bounds__(256) void k_xryg2(const float* __restrict__ x1,
                                               const double* __restrict__ meanv,
                                               const double* __restrict__ istd,
                                               const float* __restrict__ gamma,
                                               const float* __restrict__ beta,
                                               const float* __restrict__ W2,
                                               const double* __restrict__ dinv2,
                                               float* __restrict__ g2) {
  __shared__ float xs[4 * 64];
  int t = threadIdx.x;
  int t2 = blockIdx.x * 256 + t;
  int c = t & 63;
  float v = gamma[c] * (float)(((double)x1[t2] - meanv[c]) * istd[c]) + beta[c];
  xs[t] = v > 0.0f ? v : 0.0f;
  __syncthreads();
  const float* xrow = xs + (t >> 6) * 64;
  float a = 0.0f;
#pragma unroll 8
  for (int k = 0; k < HID; ++k) a = fmaf(xrow[k], W2[k * HID + c], a);
  int j = t2 >> 6;
  g2[t2] = (float)(dinv2[j] * (double)a);
}

// ---------- epilogue 2: x2 = dinv2_i*(sum + g2_i) + b2 ----------
__global__ __launch_bounds__(256) void k_ep2(const float* __restrict__ accb,
                                             const float* __restrict__ g2,
                                             const double* __restrict__ dinv2,
                                             const float* __restrict__ b2p,
                                             float* __restrict__ x2out) {
  int t = blockIdx.x * 256 + threadIdx.x;
  int i = t >> 6, c = t & 63;
  double ss = 0.0;
  for (int s = 0; s < 8; ++s) ss += (double)accb[(size_t)s * NN * HID + t];
  x2out[t] = (float)(dinv2[i] * (ss + (double)g2[t])) + b2p[c];
}

extern "C" void kernel_launch(void* const* d_in, const int* in_sizes, int n_in,
                              void* d_out, int out_size, void* d_ws, size_t ws_size,
                              hipStream_t stream) {
  const float* x = (const float*)d_in[0];
  const int* ei = (const int*)d_in[1];
  const float* W1 = (const float*)d_in[2];
  const float* b1 = (const float*)d_in[3];
  const float* W2 = (const float*)d_in[4];
  const float* b2 = (const float*)d_in[5];
  const float* gamma = (const float*)d_in[6];
  const float* beta = (const float*)d_in[7];
  const float* prelu = (const float*)d_in[8];
  const float* u = (const float*)d_in[9];
  int E = in_sizes[1] / 2;

  float* out = (float*)d_out;
  float* o_x2 = out;
  float* o_z = out + (size_t)NN * HID;
  float* o_adjS = out + (size_t)2 * NN * HID;
  float* o_adjL = o_adjS + (size_t)NN * NN;
  float* o_adjO = o_adjL + (size_t)NN * NN;

  // workspace layout: region A (phase-1, later overlaid by accb), region B persistent.
  // bitO (4,718,592 B) overlays x1/gg: bitO lifetime ends at k_tile; x1/gg are first
  // written after k_tile. bitT (transposed sample bits) is appended.
  char* w = (char*)d_ws;
  double* hxw = (double*)w;                        // 3,145,728 B
  double* hagg = (double*)(w + 3145728);           // 3,145,728 B
  double* dinv = (double*)(w + 6291456);           // 49,152 B
  int* deg = (int*)(w + 6340608);                  // 24,576 B
  float* accb = (float*)w;                         // 12,582,912 B, overlays dead region A
  double* dinv2 = (double*)(w + 12582912);         // 49,152 B
  u64* lmax = (u64*)(w + 12632064);                // 8 B
  double* meanv = (double*)(w + 12632128);         // 512 B
  double* istd = (double*)(w + 12632640);          // 512 B
  float* x1 = (float*)(w + 12633152);              // 1,572,864 B
  float* gg = (float*)(w + 14206016);              // 1,572,864 B
  float* g2 = (float*)(w + 17351744);              // 1,572,864 B
  u64* bitO = (u64*)(w + 12633152);                // 4,718,592 B, overlays x1/gg
  u64* bitT = (u64*)(w + 18924608);                // 4,718,592 B -> total 23,643,200 B

  hipMemsetAsync(deg, 0, NN * sizeof(int), stream);
  hipMemsetAsync(hagg, 0, (size_t)NN * HID * sizeof(double), stream);
  hipMemsetAsync(lmax, 0, sizeof(u64), stream);
  hipMemsetAsync(bitO, 0, (size_t)NN * NW * sizeof(u64), stream);

  k_hxw<<<NN * HID / 256, 256, 0, stream>>>(x, W1, hxw);
  k_edges<<<(E + 255) / 256, 256, 0, stream>>>(ei, E, deg, bitO);
  k_dinv<<<NN / 256, 256, 0, stream>>>(deg, dinv);
  k_agg<<<(E * HID + 255) / 256, 256, 0, stream>>>(ei, E, hxw, dinv, hagg);
  k_sblmax<<<NN / 256, 256, 0, stream>>>(hxw, dinv, b1, hagg, lmax);
  dim3 gt(96, 96);
  k_tile<<<gt, 256, 0, stream>>>(hagg, lmax, u, bitO, o_adjL, o_adjS, o_adjO, bitT);
  k_rsg<<<NN / 256, 256, 0, stream>>>(bitT, hxw, dinv2, gg);
  dim3 ga(96, 8);
  k_anmm<<<ga, 256, 0, stream>>>(bitT, gg, accb);
  k_ep1<<<NN * HID / 256, 256, 0, stream>>>(accb, gg, dinv2, b1, prelu, x1, o_z);
  k_bnstats<<<HID, 256, 0, stream>>>(x1, meanv, istd);
  k_xryg2<<<NN * HID / 256, 256, 0, stream>>>(x1, meanv, istd, gamma, beta, W2, dinv2, g2);
  k_anmm<<<ga, 256, 0, stream>>>(bitT, g2, accb);
  k_ep2<<<NN * HID / 256, 256, 0, stream>>>(accb, g2, dinv2, b2, o_x2);
}

// Round 4
// 1083.286 us; speedup vs baseline: 1.1142x; 1.1142x over previous
//
#include <hip/hip_runtime.h>
#include <math.h>

#define NN 6144
#define FIN 256
#define HID 64
#define NW 96  // NN/64 bitmask words per row
typedef unsigned long long u64;

// All inputs and outputs are float32 (reference dtypes). d_out is float*.

// ---------- hxw = x @ W1 (fp64 accumulate; feeds decision-critical chain) ----------
__global__ __launch_bounds__(256) void k_hxw(const float* __restrict__ x,
                                             const float* __restrict__ W1,
                                             double* __restrict__ hxw) {
  int t = blockIdx.x * 256 + threadIdx.x;   // exactly N*64 threads
  int i = t >> 6, c = t & 63;
  const float* xr = x + (size_t)i * FIN;
  double a = 0.0;
#pragma unroll 8
  for (int k = 0; k < FIN; ++k)
    a = fma((double)xr[k], (double)W1[k * HID + c], a);
  hxw[t] = a;
}

// ---------- degree count + adj_orig bitmask scatter (float adjO written by k_tile) ----------
__global__ __launch_bounds__(256) void k_edges(const int* __restrict__ ei, int E,
                                               int* __restrict__ deg,
                                               u64* __restrict__ bitO) {
  int e = blockIdx.x * 256 + threadIdx.x;
  if (e >= E) return;
  int s = ei[e], d = ei[E + e];
  atomicAdd(&deg[d], 1);
  atomicOr(&bitO[(size_t)s * NW + (d >> 6)], 1ull << (d & 63));
}

__global__ __launch_bounds__(256) void k_dinv(const int* __restrict__ deg,
                                              double* __restrict__ dinv) {
  int i = blockIdx.x * 256 + threadIdx.x;
  if (i < NN) dinv[i] = 1.0 / sqrt((double)(deg[i] + 1));  // +1: self-loop
}

// ---------- GCN edge aggregation (fp64 atomics) ----------
__global__ __launch_bounds__(256) void k_agg(const int* __restrict__ ei, int E,
                                             const double* __restrict__ hxw,
                                             const double* __restrict__ dinv,
                                             double* __restrict__ hagg) {
  int t = blockIdx.x * 256 + threadIdx.x;
  if (t >= E * HID) return;
  int e = t >> 6, c = t & 63;
  int s = ei[e], d = ei[E + e];
  atomicAdd(&hagg[(size_t)d * HID + c], hxw[(size_t)s * HID + c] * (dinv[s] * dinv[d]));
}

// ---------- self-loop term + bias ----------
__global__ __launch_bounds__(256) void k_selfbias(const double* __restrict__ hxw,
                                                  const double* __restrict__ dinv,
                                                  const float* __restrict__ b1,
                                                  double* __restrict__ hagg) {
  int t = blockIdx.x * 256 + threadIdx.x;
  int i = t >> 6, c = t & 63;
  hagg[t] += hxw[t] * dinv[i] * dinv[i] + (double)b1[c];
}

// ---------- Lmax = max_i ||h_i||^2 (== global max of h h^T by Cauchy-Schwarz) ----------
// Same sequential fma chain order (c ascending) as k_tile's diagonal accumulation -> bitwise match.
__global__ __launch_bounds__(256) void k_lmax(const double* __restrict__ h,
                                              u64* __restrict__ lmax) {
  __shared__ double red[256];
  int i = blockIdx.x * 256 + threadIdx.x;
  const double* hr = h + (size_t)i * HID;
  double s = 0.0;
  for (int c = 0; c < HID; ++c) s = fma(hr[c], hr[c], s);
  red[threadIdx.x] = s;
  __syncthreads();
  for (int w = 128; w > 0; w >>= 1) {
    if (threadIdx.x < w) {
      double o = red[threadIdx.x + w];
      if (o > red[threadIdx.x]) red[threadIdx.x] = o;
    }
    __syncthreads();
  }
  if (threadIdx.x == 0)
    atomicMax(lmax, (u64)__double_as_longlong(red[0]));  // vals > 0: bits monotone
}

// 16 fp64 fmas for one k-substep; a?s are scalars (rows ty+16p), cv?s are scalars (cols tx+16q).
#define FMA16D(A0, A1, A2, A3, C0, C1, C2, C3)                                   \
  acc[0][0] = fma(A0, C0, acc[0][0]); acc[0][1] = fma(A0, C1, acc[0][1]);        \
  acc[0][2] = fma(A0, C2, acc[0][2]); acc[0][3] = fma(A0, C3, acc[0][3]);        \
  acc[1][0] = fma(A1, C0, acc[1][0]); acc[1][1] = fma(A1, C1, acc[1][1]);        \
  acc[1][2] = fma(A1, C2, acc[1][2]); acc[1][3] = fma(A1, C3, acc[1][3]);        \
  acc[2][0] = fma(A2, C0, acc[2][0]); acc[2][1] = fma(A2, C1, acc[2][1]);        \
  acc[2][2] = fma(A2, C2, acc[2][2]); acc[2][3] = fma(A2, C3, acc[2][3]);        \
  acc[3][0] = fma(A3, C0, acc[3][0]); acc[3][1] = fma(A3, C1, acc[3][1]);        \
  acc[3][2] = fma(A3, C2, acc[3][2]); acc[3][3] = fma(A3, C3, acc[3][3]);

// ---------- big fused N^2 kernel: L = h h^T tile, adj_logits + straight-through sample ----------
// round(sigmoid(logit(p)+logit(u))) == (p > 1-u): logit strictly monotone, tie -> 0 (round-half-even).
// Grid (96,96); blocks with J<I exit; block (I,J), I<J also writes mirrored (J,I) tiles via LDS transpose.
// adjO (float) is expanded from bitO here. adjS bits go to bitT in TRANSPOSED [Jblock][row] layout.
__global__ __launch_bounds__(256) void k_tile(const double* __restrict__ h,
                                              const u64* __restrict__ lmaxp,
                                              const float* __restrict__ u,
                                              const u64* __restrict__ bitO,
                                              float* __restrict__ adjL,
                                              float* __restrict__ adjS,
                                              float* __restrict__ adjO,
                                              u64* __restrict__ bitT) {
  int I = blockIdx.y, J = blockIdx.x;
  if (J < I) return;
  __shared__ __align__(16) double smem[2 * 64 * 34];  // 34,816 B
  double* As = smem;                                  // 64x34
  double* Bs = smem + 64 * 34;
  float* Ls = (float*)smem;                           // 64x68 f32 (17,408 B), aliases As
  float* Ss = ((float*)smem) + 64 * 68;               // 64x68 f32, aliases Bs
  int t = threadIdx.x;
  int tx = t & 15, ty = t >> 4;
  double acc[4][4];
#pragma unroll
  for (int p = 0; p < 4; ++p)
#pragma unroll
    for (int q = 0; q < 4; ++q) acc[p][q] = 0.0;
  const double* hI = h + (size_t)I * 64 * HID;
  const double* hJ = h + (size_t)J * 64 * HID;
  for (int k0 = 0; k0 < 64; k0 += 32) {
    __syncthreads();
    for (int idx = t; idx < 1024; idx += 256) {
      int r = idx >> 4, k2 = (idx & 15) << 1;
      *(double2*)&As[r * 34 + k2] = *(const double2*)&hI[r * 64 + k0 + k2];
      *(double2*)&Bs[r * 34 + k2] = *(const double2*)&hJ[r * 64 + k0 + k2];
    }
    __syncthreads();
#pragma unroll 8
    for (int k = 0; k < 32; k += 2) {
      double2 A0 = *(const double2*)&As[ty * 34 + k];
      double2 A1 = *(const double2*)&As[(ty + 16) * 34 + k];
      double2 A2 = *(const double2*)&As[(ty + 32) * 34 + k];
      double2 A3 = *(const double2*)&As[(ty + 48) * 34 + k];
      double2 C0 = *(const double2*)&Bs[tx * 34 + k];
      double2 C1 = *(const double2*)&Bs[(tx + 16) * 34 + k];
      double2 C2 = *(const double2*)&Bs[(tx + 32) * 34 + k];
      double2 C3 = *(const double2*)&Bs[(tx + 48) * 34 + k];
      FMA16D(A0.x, A1.x, A2.x, A3.x, C0.x, C1.x, C2.x, C3.x)  // k
      FMA16D(A0.y, A1.y, A2.y, A3.y, C0.y, C1.y, C2.y, C3.y)  // k+1
    }
  }
  __syncthreads();  // As/Bs dead from here; Ls/Ss may overwrite
  double Lmax = __longlong_as_double((long long)(*lmaxp));
  bool diag = (I == J);
#pragma unroll
  for (int p = 0; p < 4; ++p) {
    int r = ty + 16 * p;
    int gi = I * 64 + r;
    u64 wO = bitO[(size_t)gi * NW + J];  // directed bits, row gi, col-block J
    float sv[4];
#pragma unroll
    for (int q = 0; q < 4; ++q) {
      int c = tx + 16 * q;
      int gj = J * 64 + c;
      double L = acc[p][q];
      float lf = (float)L;
      adjL[(size_t)gi * NN + gj] = lf;
      adjO[(size_t)gi * NN + gj] = (float)((wO >> c) & 1ull);
      float stv;
      if (diag && r == c) {
        stv = 1.0f;  // fill_diagonal_(1)
      } else {
        // only the upper-triangle (a<b) entry decides; L[a,b]==L[b,a] bitwise
        int ga = gi < gj ? gi : gj, gb = gi < gj ? gj : gi;
        size_t ab = (size_t)ga * NN + gb;
        double uu = (double)u[ab];
        double ao = (double)(int)((bitO[(size_t)ga * NW + (gb >> 6)] >> (gb & 63)) & 1ull);
        double ep = 0.8 * (L / Lmax) + 0.2 * ao;
        if (ep < 0.0) ep = 0.0;
        double pl = ep;
        if (pl < 1e-6) pl = 1e-6;
        double hi = 1.0 - 1e-6;
        if (pl > hi) pl = hi;
        stv = (pl > 1.0 - uu) ? 1.0f : 0.0f;  // == round(sigmoid(logit(pl)+logit(uu)))
      }
      sv[q] = stv;
      adjS[(size_t)gi * NN + gj] = stv;
      if (!diag) {
        Ls[c * 68 + r] = lf;   // store transposed for mirror tile
        Ss[c * 68 + r] = stv;
      }
    }
    // pack this row's 64 sample bits: wave lane l = (ty&3)*16+tx holds (row ty+16p, col tx+16q)
    u64 word = 0;
#pragma unroll
    for (int q = 0; q < 4; ++q) {
      u64 m = __ballot(sv[q] > 0.5f);
      word |= ((m >> ((ty & 3) * 16)) & 0xFFFFull) << (16 * q);
    }
    if (tx == 0) bitT[(size_t)J * NN + gi] = word;  // transposed: [col-block][row]
  }
  if (!diag) {
    __syncthreads();
    // mirror float tiles, float4-vectorized (stride 68*4 B = 272 -> 16B aligned rows)
    for (int i4 = t; i4 < 1024; i4 += 256) {
      int a = i4 >> 4, b4 = (i4 & 15) << 2;
      int grow = J * 64 + a;
      size_t off = (size_t)grow * NN + (I * 64 + b4);
      *(float4*)(adjL + off) = *(const float4*)&Ls[a * 68 + b4];
      *(float4*)(adjS + off) = *(const float4*)&Ss[a * 68 + b4];
      u64 wOm = bitO[(size_t)grow * NW + I];  // directed bits row grow, col-block I
      *(float4*)(adjO + off) = make_float4((float)((wOm >> b4) & 1ull),
                                           (float)((wOm >> (b4 + 1)) & 1ull),
                                           (float)((wOm >> (b4 + 2)) & 1ull),
                                           (float)((wOm >> (b4 + 3)) & 1ull));
    }
    // mirror bits: per wave-iteration all 64 lanes hold one row (a = 4*k2 + wave), col = lane
    for (int k2 = 0; k2 < 16; ++k2) {
      int idx = t + (k2 << 8);
      int a = idx >> 6, b = idx & 63;
      u64 m = __ballot(Ss[a * 68 + b] > 0.5f);
      if ((t & 63) == 0) bitT[(size_t)I * NN + (J * 64 + a)] = m;
    }
  }
}

// ---------- row sums of adj_sampled via popcount (transposed layout: coalesced) ----------
__global__ __launch_bounds__(256) void k_rowsumB(const u64* __restrict__ bitT,
                                                 double* __restrict__ dinv2) {
  int i = blockIdx.x * 256 + threadIdx.x;
  int cnt = 0;
#pragma unroll
  for (int J = 0; J < NW; ++J) cnt += __popcll(bitT[(size_t)J * NN + i]);
  dinv2[i] = 1.0 / sqrt((double)(cnt + 1));
}

// ---------- g[j,c] = dinv2[j] * hxw[j,c] (fp32 for the continuous path) ----------
__global__ __launch_bounds__(256) void k_gscale(const double* __restrict__ hv,
                                                const double* __restrict__ dinv2,
                                                float* __restrict__ g) {
  int t = blockIdx.x * 256 + threadIdx.x;
  int j = t >> 6;
  g[t] = (float)(dinv2[j] * hv[t]);
}

// 16 fp32 fmas for one j-substep.
#define FMA16F(A0, A1, A2, A3, CV)                                                   \
  acc[0][0] = fmaf(A0, CV.x, acc[0][0]); acc[0][1] = fmaf(A0, CV.y, acc[0][1]);      \
  acc[0][2] = fmaf(A0, CV.z, acc[0][2]); acc[0][3] = fmaf(A0, CV.w, acc[0][3]);      \
  acc[1][0] = fmaf(A1, CV.x, acc[1][0]); acc[1][1] = fmaf(A1, CV.y, acc[1][1]);      \
  acc[1][2] = fmaf(A1, CV.z, acc[1][2]); acc[1][3] = fmaf(A1, CV.w, acc[1][3]);      \
  acc[2][0] = fmaf(A2, CV.x, acc[2][0]); acc[2][1] = fmaf(A2, CV.y, acc[2][1]);      \
  acc[2][2] = fmaf(A2, CV.z, acc[2][2]); acc[2][3] = fmaf(A2, CV.w, acc[2][3]);      \
  acc[3][0] = fmaf(A3, CV.x, acc[3][0]); acc[3][1] = fmaf(A3, CV.y, acc[3][1]);      \
  acc[3][2] = fmaf(A3, CV.z, acc[3][2]); acc[3][3] = fmaf(A3, CV.w, acc[3][3]);

// ---------- dense An-matmul partial from bitmask: slice s sums j in [s*768, (s+1)*768) ----------
// ONLY change vs the 1046 us build: the B-operand (g tile) is read directly from global
// memory instead of a gs[] LDS stage. The 16 KB g-tile fits L1 and the access is identical
// across the block's 4 waves (256 B contiguous per 16-lane group), so reads are L1-hits;
// this removes ~half the unique LDS bandwidth plus the staging writes from the LDS pipe.
// as[] expansion, operand values, and fma order (j asc, Jt asc) unchanged -> bitwise identical.
__global__ __launch_bounds__(256) void k_anmm(const u64* __restrict__ bitT,
                                              const float* __restrict__ g,
                                              float* __restrict__ accb) {
  int I = blockIdx.x;  // 0..95 row block
  int s = blockIdx.y;  // 0..7 split-K slice
  __shared__ __align__(16) float as[64 * 68];  // 17,408 B
  int t = threadIdx.x, tx = t & 15, ty = t >> 4;
  float acc[4][4];
#pragma unroll
  for (int p = 0; p < 4; ++p)
#pragma unroll
    for (int q = 0; q < 4; ++q) acc[p][q] = 0.0f;
  for (int Jt = s * 12; Jt < (s + 1) * 12; ++Jt) {
    __syncthreads();
    for (int idx = t; idx < 4096; idx += 256) {
      int r = idx >> 6, cc = idx & 63;
      u64 w = bitT[(size_t)Jt * NN + I * 64 + r];  // wave-uniform word, L2-resident
      as[r * 68 + cc] = (float)((w >> cc) & 1ull);
    }
    __syncthreads();
    const float* gJ = g + (size_t)Jt * 64 * HID + (tx << 2);
#pragma unroll 2
    for (int j0 = 0; j0 < 64; j0 += 4) {
      float4 a0v = *(const float4*)&as[ty * 68 + j0];
      float4 a1v = *(const float4*)&as[(ty + 16) * 68 + j0];
      float4 a2v = *(const float4*)&as[(ty + 32) * 68 + j0];
      float4 a3v = *(const float4*)&as[(ty + 48) * 68 + j0];
      float4 cv0 = *(const float4*)&gJ[(size_t)j0 * HID];
      float4 cv1 = *(const float4*)&gJ[(size_t)(j0 + 1) * HID];
      float4 cv2 = *(const float4*)&gJ[(size_t)(j0 + 2) * HID];
      float4 cv3 = *(const float4*)&gJ[(size_t)(j0 + 3) * HID];
      FMA16F(a0v.x, a1v.x, a2v.x, a3v.x, cv0)  // j0   (ascending j, same order as before)
      FMA16F(a0v.y, a1v.y, a2v.y, a3v.y, cv1)  // j0+1
      FMA16F(a0v.z, a1v.z, a2v.z, a3v.z, cv2)  // j0+2
      FMA16F(a0v.w, a1v.w, a2v.w, a3v.w, cv3)  // j0+3
    }
  }
  float* out = accb + (size_t)s * NN * HID;
#pragma unroll
  for (int p = 0; p < 4; ++p) {
    float4 v = make_float4(acc[p][0], acc[p][1], acc[p][2], acc[p][3]);
    *(float4*)&out[(size_t)(I * 64 + ty + 16 * p) * HID + (tx << 2)] = v;
  }
}

// ---------- epilogue 1: x1 = dinv2_i*(sum + g_i) + b1; z = PReLU(x1) ----------
__global__ __launch_bounds__(256) void k_ep1(const float* __restrict__ accb,
                                             const float* __restrict__ g,
                                             const double* __restrict__ dinv2,
                                             const float* __restrict__ b1,
                                             const float* __restrict__ prelu,
                                             float* __restrict__ x1,
                                             float* __restrict__ zout) {
  int t = blockIdx.x * 256 + threadIdx.x;
  int i = t >> 6, c = t & 63;
  double ss = 0.0;
  for (int s = 0; s < 8; ++s) ss += (double)accb[(size_t)s * NN * HID + t];
  float v = (float)(dinv2[i] * (ss + (double)g[t])) + b1[c];
  x1[t] = v;
  float pa = prelu[0];
  zout[t] = v >= 0.0f ? v : pa * v;
}

// ---------- BN stats (biased var, training mode) ----------
__global__ __launch_bounds__(256) void k_bnstats(const float* __restrict__ x1,
                                                 double* __restrict__ meanv,
                                                 double* __restrict__ istd) {
  __shared__ double r1[256], r2[256];
  int c = blockIdx.x;
  double s1 = 0.0, s2 = 0.0;
  for (int i = threadIdx.x; i < NN; i += 256) {
    double v = (double)x1[(size_t)i * HID + c];
    s1 += v;
    s2 += v * v;
  }
  r1[threadIdx.x] = s1;
  r2[threadIdx.x] = s2;
  __syncthreads();
  for (int w = 128; w > 0; w >>= 1) {
    if (threadIdx.x < w) {
      r1[threadIdx.x] += r1[threadIdx.x + w];
      r2[threadIdx.x] += r2[threadIdx.x + w];
    }
    __syncthreads();
  }
  if (threadIdx.x == 0) {
    double m = r1[0] / (double)NN;
    double var = r2[0] / (double)NN - m * m;
    meanv[c] = m;
    istd[c] = 1.0 / sqrt(var + 1e-5);
  }
}

// ---------- fused BN-apply + ReLU + (xr @ W2) + dinv2 scale ----------
__global__ __launch_bounds__(256) void k_xryg2(const float* __restrict__ x1,
                                               const double* __restrict__ meanv,
                                               const double* __restrict__ istd,
                                               const float* __restrict__ gamma,
                                               const float* __restrict__ beta,
                                               const float* __restrict__ W2,
                                               const double* __restrict__ dinv2,
                                               float* __restrict__ g2) {
  __shared__ float xs[4 * 64];
  int t = threadIdx.x;
  int t2 = blockIdx.x * 256 + t;
  int c = t & 63;
  float v = gamma[c] * (float)(((double)x1[t2] - meanv[c]) * istd[c]) + beta[c];
  xs[t] = v > 0.0f ? v : 0.0f;
  __syncthreads();
  const float* xrow = xs + (t >> 6) * 64;
  float a = 0.0f;
#pragma unroll 8
  for (int k = 0; k < HID; ++k) a = fmaf(xrow[k], W2[k * HID + c], a);
  int j = t2 >> 6;
  g2[t2] = (float)(dinv2[j] * (double)a);
}

// ---------- epilogue 2: x2 = dinv2_i*(sum + g2_i) + b2 ----------
__global__ __launch_bounds__(256) void k_ep2(const float* __restrict__ accb,
                                             const float* __restrict__ g2,
                                             const double* __restrict__ dinv2,
                                             const float* __restrict__ b2p,
                                             float* __restrict__ x2out) {
  int t = blockIdx.x * 256 + threadIdx.x;
  int i = t >> 6, c = t & 63;
  double ss = 0.0;
  for (int s = 0; s < 8; ++s) ss += (double)accb[(size_t)s * NN * HID + t];
  x2out[t] = (float)(dinv2[i] * (ss + (double)g2[t])) + b2p[c];
}

extern "C" void kernel_launch(void* const* d_in, const int* in_sizes, int n_in,
                              void* d_out, int out_size, void* d_ws, size_t ws_size,
                              hipStream_t stream) {
  const float* x = (const float*)d_in[0];
  const int* ei = (const int*)d_in[1];
  const float* W1 = (const float*)d_in[2];
  const float* b1 = (const float*)d_in[3];
  const float* W2 = (const float*)d_in[4];
  const float* b2 = (const float*)d_in[5];
  const float* gamma = (const float*)d_in[6];
  const float* beta = (const float*)d_in[7];
  const float* prelu = (const float*)d_in[8];
  const float* u = (const float*)d_in[9];
  int E = in_sizes[1] / 2;

  float* out = (float*)d_out;
  float* o_x2 = out;
  float* o_z = out + (size_t)NN * HID;
  float* o_adjS = out + (size_t)2 * NN * HID;
  float* o_adjL = o_adjS + (size_t)NN * NN;
  float* o_adjO = o_adjL + (size_t)NN * NN;

  // workspace layout: region A (phase-1, later overlaid by accb), region B persistent.
  // bitO (4,718,592 B) overlays x1/gg: bitO lifetime ends at k_tile; x1/gg are first
  // written after k_tile. bitT (transposed sample bits) is appended.
  char* w = (char*)d_ws;
  double* hxw = (double*)w;                        // 3,145,728 B
  double* hagg = (double*)(w + 3145728);           // 3,145,728 B
  double* dinv = (double*)(w + 6291456);           // 49,152 B
  int* deg = (int*)(w + 6340608);                  // 24,576 B
  float* accb = (float*)w;                         // 12,582,912 B, overlays dead region A
  double* dinv2 = (double*)(w + 12582912);         // 49,152 B
  u64* lmax = (u64*)(w + 12632064);                // 8 B
  double* meanv = (double*)(w + 12632128);         // 512 B
  double* istd = (double*)(w + 12632640);          // 512 B
  float* x1 = (float*)(w + 12633152);              // 1,572,864 B
  float* gg = (float*)(w + 14206016);              // 1,572,864 B
  float* g2 = (float*)(w + 17351744);              // 1,572,864 B
  u64* bitO = (u64*)(w + 12633152);                // 4,718,592 B, overlays x1/gg
  u64* bitT = (u64*)(w + 18924608);                // 4,718,592 B -> total 23,643,200 B

  hipMemsetAsync(deg, 0, NN * sizeof(int), stream);
  hipMemsetAsync(hagg, 0, (size_t)NN * HID * sizeof(double), stream);
  hipMemsetAsync(lmax, 0, sizeof(u64), stream);
  hipMemsetAsync(bitO, 0, (size_t)NN * NW * sizeof(u64), stream);

  k_hxw<<<NN * HID / 256, 256, 0, stream>>>(x, W1, hxw);
  k_edges<<<(E + 255) / 256, 256, 0, stream>>>(ei, E, deg, bitO);
  k_dinv<<<NN / 256, 256, 0, stream>>>(deg, dinv);
  k_agg<<<(E * HID + 255) / 256, 256, 0, stream>>>(ei, E, hxw, dinv, hagg);
  k_selfbias<<<NN * HID / 256, 256, 0, stream>>>(hxw, dinv, b1, hagg);
  k_lmax<<<NN / 256, 256, 0, stream>>>(hagg, lmax);
  dim3 gt(96, 96);
  k_tile<<<gt, 256, 0, stream>>>(hagg, lmax, u, bitO, o_adjL, o_adjS, o_adjO, bitT);
  k_rowsumB<<<NN / 256, 256, 0, stream>>>(bitT, dinv2);
  k_gscale<<<NN * HID / 256, 256, 0, stream>>>(hxw, dinv2, gg);
  dim3 ga(96, 8);
  k_anmm<<<ga, 256, 0, stream>>>(bitT, gg, accb);
  k_ep1<<<NN * HID / 256, 256, 0, stream>>>(accb, gg, dinv2, b1, prelu, x1, o_z);
  k_bnstats<<<HID, 256, 0, stream>>>(x1, meanv, istd);
  k_xryg2<<<NN * HID / 256, 256, 0, stream>>>(x1, meanv, istd, gamma, beta, W2, dinv2, g2);
  k_anmm<<<ga, 256, 0, stream>>>(bitT, g2, accb);
  k_ep2<<<NN * HID / 256, 256, 0, stream>>>(accb, g2, dinv2, b2, o_x2);
}

// Round 5
// 1033.650 us; speedup vs baseline: 1.1678x; 1.0480x over previous
//
#include <hip/hip_runtime.h>
#include <math.h>

#define NN 6144
#define FIN 256
#define HID 64
#define NW 96  // NN/64 bitmask words per row
typedef unsigned long long u64;

// All inputs and outputs are float32 (reference dtypes). d_out is float*.

// ---------- hxw = x @ W1 (fp64 accumulate; feeds decision-critical chain) ----------
__global__ __launch_bounds__(256) void k_hxw(const float* __restrict__ x,
                                             const float* __restrict__ W1,
                                             double* __restrict__ hxw) {
  int t = blockIdx.x * 256 + threadIdx.x;   // exactly N*64 threads
  int i = t >> 6, c = t & 63;
  const float* xr = x + (size_t)i * FIN;
  double a = 0.0;
#pragma unroll 8
  for (int k = 0; k < FIN; ++k)
    a = fma((double)xr[k], (double)W1[k * HID + c], a);
  hxw[t] = a;
}

// ---------- degree count + adj_orig bitmask scatter (float adjO written by k_tile) ----------
__global__ __launch_bounds__(256) void k_edges(const int* __restrict__ ei, int E,
                                               int* __restrict__ deg,
                                               u64* __restrict__ bitO) {
  int e = blockIdx.x * 256 + threadIdx.x;
  if (e >= E) return;
  int s = ei[e], d = ei[E + e];
  atomicAdd(&deg[d], 1);
  atomicOr(&bitO[(size_t)s * NW + (d >> 6)], 1ull << (d & 63));
}

__global__ __launch_bounds__(256) void k_dinv(const int* __restrict__ deg,
                                              double* __restrict__ dinv) {
  int i = blockIdx.x * 256 + threadIdx.x;
  if (i < NN) dinv[i] = 1.0 / sqrt((double)(deg[i] + 1));  // +1: self-loop
}

// ---------- GCN edge aggregation (fp64 atomics) ----------
__global__ __launch_bounds__(256) void k_agg(const int* __restrict__ ei, int E,
                                             const double* __restrict__ hxw,
                                             const double* __restrict__ dinv,
                                             double* __restrict__ hagg) {
  int t = blockIdx.x * 256 + threadIdx.x;
  if (t >= E * HID) return;
  int e = t >> 6, c = t & 63;
  int s = ei[e], d = ei[E + e];
  atomicAdd(&hagg[(size_t)d * HID + c], hxw[(size_t)s * HID + c] * (dinv[s] * dinv[d]));
}

// ---------- self-loop term + bias ----------
__global__ __launch_bounds__(256) void k_selfbias(const double* __restrict__ hxw,
                                                  const double* __restrict__ dinv,
                                                  const float* __restrict__ b1,
                                                  double* __restrict__ hagg) {
  int t = blockIdx.x * 256 + threadIdx.x;
  int i = t >> 6, c = t & 63;
  hagg[t] += hxw[t] * dinv[i] * dinv[i] + (double)b1[c];
}

// ---------- Lmax = max_i ||h_i||^2 (== global max of h h^T by Cauchy-Schwarz) ----------
// Same sequential fma chain order (c ascending) as k_tile's diagonal accumulation -> bitwise match.
__global__ __launch_bounds__(256) void k_lmax(const double* __restrict__ h,
                                              u64* __restrict__ lmax) {
  __shared__ double red[256];
  int i = blockIdx.x * 256 + threadIdx.x;
  const double* hr = h + (size_t)i * HID;
  double s = 0.0;
  for (int c = 0; c < HID; ++c) s = fma(hr[c], hr[c], s);
  red[threadIdx.x] = s;
  __syncthreads();
  for (int w = 128; w > 0; w >>= 1) {
    if (threadIdx.x < w) {
      double o = red[threadIdx.x + w];
      if (o > red[threadIdx.x]) red[threadIdx.x] = o;
    }
    __syncthreads();
  }
  if (threadIdx.x == 0)
    atomicMax(lmax, (u64)__double_as_longlong(red[0]));  // vals > 0: bits monotone
}

// 16 fp64 fmas for one k-substep; a?s are scalars (rows ty+16p), cv?s are scalars (cols tx+16q).
#define FMA16D(A0, A1, A2, A3, C0, C1, C2, C3)                                   \
  acc[0][0] = fma(A0, C0, acc[0][0]); acc[0][1] = fma(A0, C1, acc[0][1]);        \
  acc[0][2] = fma(A0, C2, acc[0][2]); acc[0][3] = fma(A0, C3, acc[0][3]);        \
  acc[1][0] = fma(A1, C0, acc[1][0]); acc[1][1] = fma(A1, C1, acc[1][1]);        \
  acc[1][2] = fma(A1, C2, acc[1][2]); acc[1][3] = fma(A1, C3, acc[1][3]);        \
  acc[2][0] = fma(A2, C0, acc[2][0]); acc[2][1] = fma(A2, C1, acc[2][1]);        \
  acc[2][2] = fma(A2, C2, acc[2][2]); acc[2][3] = fma(A2, C3, acc[2][3]);        \
  acc[3][0] = fma(A3, C0, acc[3][0]); acc[3][1] = fma(A3, C1, acc[3][1]);        \
  acc[3][2] = fma(A3, C2, acc[3][2]); acc[3][3] = fma(A3, C3, acc[3][3]);

// ---------- big fused N^2 kernel: L = h h^T tile, adj_logits + straight-through sample ----------
// round(sigmoid(logit(p)+logit(u))) == (p > 1-u): logit strictly monotone, tie -> 0 (round-half-even).
// Grid (96,96); blocks with J<I exit; block (I,J), I<J also writes mirrored (J,I) tiles via LDS transpose.
// adjO (float) is expanded from bitO here. adjS bits go to bitT in TRANSPOSED [Jblock][row] layout.
__global__ __launch_bounds__(256) void k_tile(const double* __restrict__ h,
                                              const u64* __restrict__ lmaxp,
                                              const float* __restrict__ u,
                                              const u64* __restrict__ bitO,
                                              float* __restrict__ adjL,
                                              float* __restrict__ adjS,
                                              float* __restrict__ adjO,
                                              u64* __restrict__ bitT) {
  int I = blockIdx.y, J = blockIdx.x;
  if (J < I) return;
  __shared__ __align__(16) double smem[2 * 64 * 34];  // 34,816 B
  double* As = smem;                                  // 64x34
  double* Bs = smem + 64 * 34;
  float* Ls = (float*)smem;                           // 64x68 f32 (17,408 B), aliases As
  float* Ss = ((float*)smem) + 64 * 68;               // 64x68 f32, aliases Bs
  int t = threadIdx.x;
  int tx = t & 15, ty = t >> 4;
  double acc[4][4];
#pragma unroll
  for (int p = 0; p < 4; ++p)
#pragma unroll
    for (int q = 0; q < 4; ++q) acc[p][q] = 0.0;
  const double* hI = h + (size_t)I * 64 * HID;
  const double* hJ = h + (size_t)J * 64 * HID;
  for (int k0 = 0; k0 < 64; k0 += 32) {
    __syncthreads();
    for (int idx = t; idx < 1024; idx += 256) {
      int r = idx >> 4, k2 = (idx & 15) << 1;
      *(double2*)&As[r * 34 + k2] = *(const double2*)&hI[r * 64 + k0 + k2];
      *(double2*)&Bs[r * 34 + k2] = *(const double2*)&hJ[r * 64 + k0 + k2];
    }
    __syncthreads();
#pragma unroll 8
    for (int k = 0; k < 32; k += 2) {
      double2 A0 = *(const double2*)&As[ty * 34 + k];
      double2 A1 = *(const double2*)&As[(ty + 16) * 34 + k];
      double2 A2 = *(const double2*)&As[(ty + 32) * 34 + k];
      double2 A3 = *(const double2*)&As[(ty + 48) * 34 + k];
      double2 C0 = *(const double2*)&Bs[tx * 34 + k];
      double2 C1 = *(const double2*)&Bs[(tx + 16) * 34 + k];
      double2 C2 = *(const double2*)&Bs[(tx + 32) * 34 + k];
      double2 C3 = *(const double2*)&Bs[(tx + 48) * 34 + k];
      FMA16D(A0.x, A1.x, A2.x, A3.x, C0.x, C1.x, C2.x, C3.x)  // k
      FMA16D(A0.y, A1.y, A2.y, A3.y, C0.y, C1.y, C2.y, C3.y)  // k+1
    }
  }
  __syncthreads();  // As/Bs dead from here; Ls/Ss may overwrite
  double Lmax = __longlong_as_double((long long)(*lmaxp));
  bool diag = (I == J);
#pragma unroll
  for (int p = 0; p < 4; ++p) {
    int r = ty + 16 * p;
    int gi = I * 64 + r;
    u64 wO = bitO[(size_t)gi * NW + J];  // directed bits, row gi, col-block J
    float sv[4];
#pragma unroll
    for (int q = 0; q < 4; ++q) {
      int c = tx + 16 * q;
      int gj = J * 64 + c;
      double L = acc[p][q];
      float lf = (float)L;
      adjL[(size_t)gi * NN + gj] = lf;
      adjO[(size_t)gi * NN + gj] = (float)((wO >> c) & 1ull);
      float stv;
      if (diag && r == c) {
        stv = 1.0f;  // fill_diagonal_(1)
      } else {
        // only the upper-triangle (a<b) entry decides; L[a,b]==L[b,a] bitwise
        int ga = gi < gj ? gi : gj, gb = gi < gj ? gj : gi;
        size_t ab = (size_t)ga * NN + gb;
        double uu = (double)u[ab];
        double ao = (double)(int)((bitO[(size_t)ga * NW + (gb >> 6)] >> (gb & 63)) & 1ull);
        double ep = 0.8 * (L / Lmax) + 0.2 * ao;
        if (ep < 0.0) ep = 0.0;
        double pl = ep;
        if (pl < 1e-6) pl = 1e-6;
        double hi = 1.0 - 1e-6;
        if (pl > hi) pl = hi;
        stv = (pl > 1.0 - uu) ? 1.0f : 0.0f;  // == round(sigmoid(logit(pl)+logit(uu)))
      }
      sv[q] = stv;
      adjS[(size_t)gi * NN + gj] = stv;
      if (!diag) {
        Ls[c * 68 + r] = lf;   // store transposed for mirror tile
        Ss[c * 68 + r] = stv;
      }
    }
    // pack this row's 64 sample bits: wave lane l = (ty&3)*16+tx holds (row ty+16p, col tx+16q)
    u64 word = 0;
#pragma unroll
    for (int q = 0; q < 4; ++q) {
      u64 m = __ballot(sv[q] > 0.5f);
      word |= ((m >> ((ty & 3) * 16)) & 0xFFFFull) << (16 * q);
    }
    if (tx == 0) bitT[(size_t)J * NN + gi] = word;  // transposed: [col-block][row]
  }
  if (!diag) {
    __syncthreads();
    // mirror float tiles, float4-vectorized (stride 68*4 B = 272 -> 16B aligned rows)
    for (int i4 = t; i4 < 1024; i4 += 256) {
      int a = i4 >> 4, b4 = (i4 & 15) << 2;
      int grow = J * 64 + a;
      size_t off = (size_t)grow * NN + (I * 64 + b4);
      *(float4*)(adjL + off) = *(const float4*)&Ls[a * 68 + b4];
      *(float4*)(adjS + off) = *(const float4*)&Ss[a * 68 + b4];
      u64 wOm = bitO[(size_t)grow * NW + I];  // directed bits row grow, col-block I
      *(float4*)(adjO + off) = make_float4((float)((wOm >> b4) & 1ull),
                                           (float)((wOm >> (b4 + 1)) & 1ull),
                                           (float)((wOm >> (b4 + 2)) & 1ull),
                                           (float)((wOm >> (b4 + 3)) & 1ull));
    }
    // mirror bits: per wave-iteration all 64 lanes hold one row (a = 4*k2 + wave), col = lane
    for (int k2 = 0; k2 < 16; ++k2) {
      int idx = t + (k2 << 8);
      int a = idx >> 6, b = idx & 63;
      u64 m = __ballot(Ss[a * 68 + b] > 0.5f);
      if ((t & 63) == 0) bitT[(size_t)I * NN + (J * 64 + a)] = m;
    }
  }
}

// ---------- row sums of adj_sampled via popcount (transposed layout: coalesced) ----------
__global__ __launch_bounds__(256) void k_rowsumB(const u64* __restrict__ bitT,
                                                 double* __restrict__ dinv2) {
  int i = blockIdx.x * 256 + threadIdx.x;
  int cnt = 0;
#pragma unroll
  for (int J = 0; J < NW; ++J) cnt += __popcll(bitT[(size_t)J * NN + i]);
  dinv2[i] = 1.0 / sqrt((double)(cnt + 1));
}

// ---------- g[j,c] = dinv2[j] * hxw[j,c] (fp32 for the continuous path) ----------
__global__ __launch_bounds__(256) void k_gscale(const double* __restrict__ hv,
                                                const double* __restrict__ dinv2,
                                                float* __restrict__ g) {
  int t = blockIdx.x * 256 + threadIdx.x;
  int j = t >> 6;
  g[t] = (float)(dinv2[j] * hv[t]);
}

// 16 fp32 fmas for one j-substep (B0..B3 scalar bits per row, CV float4 per 4 cols).
#define FMA16F(A0, A1, A2, A3, CV)                                                   \
  acc[0][0] = fmaf(A0, CV.x, acc[0][0]); acc[0][1] = fmaf(A0, CV.y, acc[0][1]);      \
  acc[0][2] = fmaf(A0, CV.z, acc[0][2]); acc[0][3] = fmaf(A0, CV.w, acc[0][3]);      \
  acc[1][0] = fmaf(A1, CV.x, acc[1][0]); acc[1][1] = fmaf(A1, CV.y, acc[1][1]);      \
  acc[1][2] = fmaf(A1, CV.z, acc[1][2]); acc[1][3] = fmaf(A1, CV.w, acc[1][3]);      \
  acc[2][0] = fmaf(A2, CV.x, acc[2][0]); acc[2][1] = fmaf(A2, CV.y, acc[2][1]);      \
  acc[2][2] = fmaf(A2, CV.z, acc[2][2]); acc[2][3] = fmaf(A2, CV.w, acc[2][3]);      \
  acc[3][0] = fmaf(A3, CV.x, acc[3][0]); acc[3][1] = fmaf(A3, CV.y, acc[3][1]);      \
  acc[3][2] = fmaf(A3, CV.z, acc[3][2]); acc[3][3] = fmaf(A3, CV.w, acc[3][3]);

// ---------- dense An-matmul partial: slice s sums j in [s*768, (s+1)*768) ----------
// vs the 1046 us build, ONE change: the as[] LDS tile is gone. Each thread keeps its 4
// row-words of bitT in registers (16-lane-broadcast L2 loads, issued BEFORE the barrier so
// their latency hides under gs staging) and extracts bits in the inner loop from 32-bit
// halves with compile-time shift amounts (unroll 8 -> v_bfe_u32 + v_cvt, 2 VALU ops/bit,
// <=32 live temps, no 64-bit runtime shifts -> no spill). This halves the block's LDS-pipe
// cycles (the binding resource: was ~6144 cy/block-Jt, now ~3072). The extracted values
// (float)((w>>j)&1) and the fma order (j asc, Jt asc, same split-K) are bitwise identical
// to the old as[]-expanded path -> absmax unchanged.
__global__ __launch_bounds__(256) void k_anmm(const u64* __restrict__ bitT,
                                              const float* __restrict__ g,
                                              float* __restrict__ accb) {
  int I = blockIdx.x;  // 0..95 row block
  int s = blockIdx.y;  // 0..7 split-K slice
  __shared__ __align__(16) float gs[64 * 64];  // 16,384 B
  int t = threadIdx.x, tx = t & 15, ty = t >> 4;
  float acc[4][4];
#pragma unroll
  for (int p = 0; p < 4; ++p)
#pragma unroll
    for (int q = 0; q < 4; ++q) acc[p][q] = 0.0f;
  for (int Jt = s * 12; Jt < (s + 1) * 12; ++Jt) {
    // issue the 4 broadcast row-word loads first: latency overlaps gs staging + barrier
    const u64* bw = bitT + (size_t)Jt * NN + I * 64;
    u64 w0 = bw[ty];        // 16 lanes share each word, L2-resident
    u64 w1 = bw[ty + 16];
    u64 w2 = bw[ty + 32];
    u64 w3 = bw[ty + 48];
    __syncthreads();
    for (int i4 = t; i4 < 1024; i4 += 256) {
      int r = i4 >> 4, c4 = (i4 & 15) << 2;
      *(float4*)&gs[r * 64 + c4] = *(const float4*)&g[(size_t)(Jt * 64 + r) * HID + c4];
    }
    __syncthreads();
    unsigned lo0 = (unsigned)w0, hi0 = (unsigned)(w0 >> 32);
    unsigned lo1 = (unsigned)w1, hi1 = (unsigned)(w1 >> 32);
    unsigned lo2 = (unsigned)w2, hi2 = (unsigned)(w2 >> 32);
    unsigned lo3 = (unsigned)w3, hi3 = (unsigned)(w3 >> 32);
    const float* gp = gs + (tx << 2);
#pragma unroll 8
    for (int j = 0; j < 32; ++j) {   // j ascending: identical fma order
      float4 cv = *(const float4*)&gp[j * 64];
      float b0 = (float)((lo0 >> j) & 1u);
      float b1 = (float)((lo1 >> j) & 1u);
      float b2 = (float)((lo2 >> j) & 1u);
      float b3 = (float)((lo3 >> j) & 1u);
      FMA16F(b0, b1, b2, b3, cv)
    }
#pragma unroll 8
    for (int j = 0; j < 32; ++j) {   // j+32, ascending
      float4 cv = *(const float4*)&gp[(j + 32) * 64];
      float b0 = (float)((hi0 >> j) & 1u);
      float b1 = (float)((hi1 >> j) & 1u);
      float b2 = (float)((hi2 >> j) & 1u);
      float b3 = (float)((hi3 >> j) & 1u);
      FMA16F(b0, b1, b2, b3, cv)
    }
  }
  float* out = accb + (size_t)s * NN * HID;
#pragma unroll
  for (int p = 0; p < 4; ++p) {
    float4 v = make_float4(acc[p][0], acc[p][1], acc[p][2], acc[p][3]);
    *(float4*)&out[(size_t)(I * 64 + ty + 16 * p) * HID + (tx << 2)] = v;
  }
}

// ---------- epilogue 1: x1 = dinv2_i*(sum + g_i) + b1; z = PReLU(x1) ----------
__global__ __launch_bounds__(256) void k_ep1(const float* __restrict__ accb,
                                             const float* __restrict__ g,
                                             const double* __restrict__ dinv2,
                                             const float* __restrict__ b1,
                                             const float* __restrict__ prelu,
                                             float* __restrict__ x1,
                                             float* __restrict__ zout) {
  int t = blockIdx.x * 256 + threadIdx.x;
  int i = t >> 6, c = t & 63;
  double ss = 0.0;
  for (int s = 0; s < 8; ++s) ss += (double)accb[(size_t)s * NN * HID + t];
  float v = (float)(dinv2[i] * (ss + (double)g[t])) + b1[c];
  x1[t] = v;
  float pa = prelu[0];
  zout[t] = v >= 0.0f ? v : pa * v;
}

// ---------- BN stats (biased var, training mode) ----------
__global__ __launch_bounds__(256) void k_bnstats(const float* __restrict__ x1,
                                                 double* __restrict__ meanv,
                                                 double* __restrict__ istd) {
  __shared__ double r1[256], r2[256];
  int c = blockIdx.x;
  double s1 = 0.0, s2 = 0.0;
  for (int i = threadIdx.x; i < NN; i += 256) {
    double v = (double)x1[(size_t)i * HID + c];
    s1 += v;
    s2 += v * v;
  }
  r1[threadIdx.x] = s1;
  r2[threadIdx.x] = s2;
  __syncthreads();
  for (int w = 128; w > 0; w >>= 1) {
    if (threadIdx.x < w) {
      r1[threadIdx.x] += r1[threadIdx.x + w];
      r2[threadIdx.x] += r2[threadIdx.x + w];
    }
    __syncthreads();
  }
  if (threadIdx.x == 0) {
    double m = r1[0] / (double)NN;
    double var = r2[0] / (double)NN - m * m;
    meanv[c] = m;
    istd[c] = 1.0 / sqrt(var + 1e-5);
  }
}

// ---------- fused BN-apply + ReLU + (xr @ W2) + dinv2 scale ----------
__global__ __launch_bounds__(256) void k_xryg2(const float* __restrict__ x1,
                                               const double* __restrict__ meanv,
                                               const double* __restrict__ istd,
                                               const float* __restrict__ gamma,
                                               const float* __restrict__ beta,
                                               const float* __restrict__ W2,
                                               const double* __restrict__ dinv2,
                                               float* __restrict__ g2) {
  __shared__ float xs[4 * 64];
  int t = threadIdx.x;
  int t2 = blockIdx.x * 256 + t;
  int c = t & 63;
  float v = gamma[c] * (float)(((double)x1[t2] - meanv[c]) * istd[c]) + beta[c];
  xs[t] = v > 0.0f ? v : 0.0f;
  __syncthreads();
  const float* xrow = xs + (t >> 6) * 64;
  float a = 0.0f;
#pragma unroll 8
  for (int k = 0; k < HID; ++k) a = fmaf(xrow[k], W2[k * HID + c], a);
  int j = t2 >> 6;
  g2[t2] = (float)(dinv2[j] * (double)a);
}

// ---------- epilogue 2: x2 = dinv2_i*(sum + g2_i) + b2 ----------
__global__ __launch_bounds__(256) void k_ep2(const float* __restrict__ accb,
                                             const float* __restrict__ g2,
                                             const double* __restrict__ dinv2,
                                             const float* __restrict__ b2p,
                                             float* __restrict__ x2out) {
  int t = blockIdx.x * 256 + threadIdx.x;
  int i = t >> 6, c = t & 63;
  double ss = 0.0;
  for (int s = 0; s < 8; ++s) ss += (double)accb[(size_t)s * NN * HID + t];
  x2out[t] = (float)(dinv2[i] * (ss + (double)g2[t])) + b2p[c];
}

extern "C" void kernel_launch(void* const* d_in, const int* in_sizes, int n_in,
                              void* d_out, int out_size, void* d_ws, size_t ws_size,
                              hipStream_t stream) {
  const float* x = (const float*)d_in[0];
  const int* ei = (const int*)d_in[1];
  const float* W1 = (const float*)d_in[2];
  const float* b1 = (const float*)d_in[3];
  const float* W2 = (const float*)d_in[4];
  const float* b2 = (const float*)d_in[5];
  const float* gamma = (const float*)d_in[6];
  const float* beta = (const float*)d_in[7];
  const float* prelu = (const float*)d_in[8];
  const float* u = (const float*)d_in[9];
  int E = in_sizes[1] / 2;

  float* out = (float*)d_out;
  float* o_x2 = out;
  float* o_z = out + (size_t)NN * HID;
  float* o_adjS = out + (size_t)2 * NN * HID;
  float* o_adjL = o_adjS + (size_t)NN * NN;
  float* o_adjO = o_adjL + (size_t)NN * NN;

  // workspace layout: region A (phase-1, later overlaid by accb), region B persistent.
  // bitO (4,718,592 B) overlays x1/gg: bitO lifetime ends at k_tile; x1/gg are first
  // written after k_tile. bitT (transposed sample bits) is appended.
  char* w = (char*)d_ws;
  double* hxw = (double*)w;                        // 3,145,728 B
  double* hagg = (double*)(w + 3145728);           // 3,145,728 B
  double* dinv = (double*)(w + 6291456);           // 49,152 B
  int* deg = (int*)(w + 6340608);                  // 24,576 B
  float* accb = (float*)w;                         // 12,582,912 B, overlays dead region A
  double* dinv2 = (double*)(w + 12582912);         // 49,152 B
  u64* lmax = (u64*)(w + 12632064);                // 8 B
  double* meanv = (double*)(w + 12632128);         // 512 B
  double* istd = (double*)(w + 12632640);          // 512 B
  float* x1 = (float*)(w + 12633152);              // 1,572,864 B
  float* gg = (float*)(w + 14206016);              // 1,572,864 B
  float* g2 = (float*)(w + 17351744);              // 1,572,864 B
  u64* bitO = (u64*)(w + 12633152);                // 4,718,592 B, overlays x1/gg
  u64* bitT = (u64*)(w + 18924608);                // 4,718,592 B -> total 23,643,200 B

  hipMemsetAsync(deg, 0, NN * sizeof(int), stream);
  hipMemsetAsync(hagg, 0, (size_t)NN * HID * sizeof(double), stream);
  hipMemsetAsync(lmax, 0, sizeof(u64), stream);
  hipMemsetAsync(bitO, 0, (size_t)NN * NW * sizeof(u64), stream);

  k_hxw<<<NN * HID / 256, 256, 0, stream>>>(x, W1, hxw);
  k_edges<<<(E + 255) / 256, 256, 0, stream>>>(ei, E, deg, bitO);
  k_dinv<<<NN / 256, 256, 0, stream>>>(deg, dinv);
  k_agg<<<(E * HID + 255) / 256, 256, 0, stream>>>(ei, E, hxw, dinv, hagg);
  k_selfbias<<<NN * HID / 256, 256, 0, stream>>>(hxw, dinv, b1, hagg);
  k_lmax<<<NN / 256, 256, 0, stream>>>(hagg, lmax);
  dim3 gt(96, 96);
  k_tile<<<gt, 256, 0, stream>>>(hagg, lmax, u, bitO, o_adjL, o_adjS, o_adjO, bitT);
  k_rowsumB<<<NN / 256, 256, 0, stream>>>(bitT, dinv2);
  k_gscale<<<NN * HID / 256, 256, 0, stream>>>(hxw, dinv2, gg);
  dim3 ga(96, 8);
  k_anmm<<<ga, 256, 0, stream>>>(bitT, gg, accb);
  k_ep1<<<NN * HID / 256, 256, 0, stream>>>(accb, gg, dinv2, b1, prelu, x1, o_z);
  k_bnstats<<<HID, 256, 0, stream>>>(x1, meanv, istd);
  k_xryg2<<<NN * HID / 256, 256, 0, stream>>>(x1, meanv, istd, gamma, beta, W2, dinv2, g2);
  k_anmm<<<ga, 256, 0, stream>>>(bitT, g2, accb);
  k_ep2<<<NN * HID / 256, 256, 0, stream>>>(accb, g2, dinv2, b2, o_x2);
}

// Round 6
// 1033.313 us; speedup vs baseline: 1.1681x; 1.0003x over previous
//
#include <hip/hip_runtime.h>
#include <math.h>

#define NN 6144
#define FIN 256
#define HID 64
#define NW 96  // NN/64 bitmask words per row
typedef unsigned long long u64;
typedef float v2f __attribute__((ext_vector_type(2)));

// All inputs and outputs are float32 (reference dtypes). d_out is float*.

// ---------- hxw = x @ W1 (fp64 accumulate; feeds decision-critical chain) ----------
__global__ __launch_bounds__(256) void k_hxw(const float* __restrict__ x,
                                             const float* __restrict__ W1,
                                             double* __restrict__ hxw) {
  int t = blockIdx.x * 256 + threadIdx.x;   // exactly N*64 threads
  int i = t >> 6, c = t & 63;
  const float* xr = x + (size_t)i * FIN;
  double a = 0.0;
#pragma unroll 8
  for (int k = 0; k < FIN; ++k)
    a = fma((double)xr[k], (double)W1[k * HID + c], a);
  hxw[t] = a;
}

// ---------- degree count + adj_orig bitmask scatter (float adjO written by k_tile) ----------
__global__ __launch_bounds__(256) void k_edges(const int* __restrict__ ei, int E,
                                               int* __restrict__ deg,
                                               u64* __restrict__ bitO) {
  int e = blockIdx.x * 256 + threadIdx.x;
  if (e >= E) return;
  int s = ei[e], d = ei[E + e];
  atomicAdd(&deg[d], 1);
  atomicOr(&bitO[(size_t)s * NW + (d >> 6)], 1ull << (d & 63));
}

__global__ __launch_bounds__(256) void k_dinv(const int* __restrict__ deg,
                                              double* __restrict__ dinv) {
  int i = blockIdx.x * 256 + threadIdx.x;
  if (i < NN) dinv[i] = 1.0 / sqrt((double)(deg[i] + 1));  // +1: self-loop
}

// ---------- GCN edge aggregation (fp64 atomics) ----------
__global__ __launch_bounds__(256) void k_agg(const int* __restrict__ ei, int E,
                                             const double* __restrict__ hxw,
                                             const double* __restrict__ dinv,
                                             double* __restrict__ hagg) {
  int t = blockIdx.x * 256 + threadIdx.x;
  if (t >= E * HID) return;
  int e = t >> 6, c = t & 63;
  int s = ei[e], d = ei[E + e];
  atomicAdd(&hagg[(size_t)d * HID + c], hxw[(size_t)s * HID + c] * (dinv[s] * dinv[d]));
}

// ---------- self-loop term + bias ----------
__global__ __launch_bounds__(256) void k_selfbias(const double* __restrict__ hxw,
                                                  const double* __restrict__ dinv,
                                                  const float* __restrict__ b1,
                                                  double* __restrict__ hagg) {
  int t = blockIdx.x * 256 + threadIdx.x;
  int i = t >> 6, c = t & 63;
  hagg[t] += hxw[t] * dinv[i] * dinv[i] + (double)b1[c];
}

// ---------- Lmax = max_i ||h_i||^2 (== global max of h h^T by Cauchy-Schwarz) ----------
// Same sequential fma chain order (c ascending) as k_tile's diagonal accumulation -> bitwise match.
__global__ __launch_bounds__(256) void k_lmax(const double* __restrict__ h,
                                              u64* __restrict__ lmax) {
  __shared__ double red[256];
  int i = blockIdx.x * 256 + threadIdx.x;
  const double* hr = h + (size_t)i * HID;
  double s = 0.0;
  for (int c = 0; c < HID; ++c) s = fma(hr[c], hr[c], s);
  red[threadIdx.x] = s;
  __syncthreads();
  for (int w = 128; w > 0; w >>= 1) {
    if (threadIdx.x < w) {
      double o = red[threadIdx.x + w];
      if (o > red[threadIdx.x]) red[threadIdx.x] = o;
    }
    __syncthreads();
  }
  if (threadIdx.x == 0)
    atomicMax(lmax, (u64)__double_as_longlong(red[0]));  // vals > 0: bits monotone
}

// 16 fp64 fmas for one k-substep; a?s are scalars (rows ty+16p), cv?s are scalars (cols tx+16q).
#define FMA16D(A0, A1, A2, A3, C0, C1, C2, C3)                                   \
  acc[0][0] = fma(A0, C0, acc[0][0]); acc[0][1] = fma(A0, C1, acc[0][1]);        \
  acc[0][2] = fma(A0, C2, acc[0][2]); acc[0][3] = fma(A0, C3, acc[0][3]);        \
  acc[1][0] = fma(A1, C0, acc[1][0]); acc[1][1] = fma(A1, C1, acc[1][1]);        \
  acc[1][2] = fma(A1, C2, acc[1][2]); acc[1][3] = fma(A1, C3, acc[1][3]);        \
  acc[2][0] = fma(A2, C0, acc[2][0]); acc[2][1] = fma(A2, C1, acc[2][1]);        \
  acc[2][2] = fma(A2, C2, acc[2][2]); acc[2][3] = fma(A2, C3, acc[2][3]);        \
  acc[3][0] = fma(A3, C0, acc[3][0]); acc[3][1] = fma(A3, C1, acc[3][1]);        \
  acc[3][2] = fma(A3, C2, acc[3][2]); acc[3][3] = fma(A3, C3, acc[3][3]);

// ---------- big fused N^2 kernel: L = h h^T tile, adj_logits + straight-through sample ----------
// round(sigmoid(logit(p)+logit(u))) == (p > 1-u): logit strictly monotone, tie -> 0 (round-half-even).
// Grid (96,96); blocks with J<I exit; block (I,J), I<J also writes mirrored (J,I) tiles via LDS transpose.
// adjO (float) is expanded from bitO here. adjS bits go to bitT in TRANSPOSED [Jblock][row] layout.
__global__ __launch_bounds__(256) void k_tile(const double* __restrict__ h,
                                              const u64* __restrict__ lmaxp,
                                              const float* __restrict__ u,
                                              const u64* __restrict__ bitO,
                                              float* __restrict__ adjL,
                                              float* __restrict__ adjS,
                                              float* __restrict__ adjO,
                                              u64* __restrict__ bitT) {
  int I = blockIdx.y, J = blockIdx.x;
  if (J < I) return;
  __shared__ __align__(16) double smem[2 * 64 * 34];  // 34,816 B
  double* As = smem;                                  // 64x34
  double* Bs = smem + 64 * 34;
  float* Ls = (float*)smem;                           // 64x68 f32 (17,408 B), aliases As
  float* Ss = ((float*)smem) + 64 * 68;               // 64x68 f32, aliases Bs
  int t = threadIdx.x;
  int tx = t & 15, ty = t >> 4;
  double acc[4][4];
#pragma unroll
  for (int p = 0; p < 4; ++p)
#pragma unroll
    for (int q = 0; q < 4; ++q) acc[p][q] = 0.0;
  const double* hI = h + (size_t)I * 64 * HID;
  const double* hJ = h + (size_t)J * 64 * HID;
  for (int k0 = 0; k0 < 64; k0 += 32) {
    __syncthreads();
    for (int idx = t; idx < 1024; idx += 256) {
      int r = idx >> 4, k2 = (idx & 15) << 1;
      *(double2*)&As[r * 34 + k2] = *(const double2*)&hI[r * 64 + k0 + k2];
      *(double2*)&Bs[r * 34 + k2] = *(const double2*)&hJ[r * 64 + k0 + k2];
    }
    __syncthreads();
#pragma unroll 8
    for (int k = 0; k < 32; k += 2) {
      double2 A0 = *(const double2*)&As[ty * 34 + k];
      double2 A1 = *(const double2*)&As[(ty + 16) * 34 + k];
      double2 A2 = *(const double2*)&As[(ty + 32) * 34 + k];
      double2 A3 = *(const double2*)&As[(ty + 48) * 34 + k];
      double2 C0 = *(const double2*)&Bs[tx * 34 + k];
      double2 C1 = *(const double2*)&Bs[(tx + 16) * 34 + k];
      double2 C2 = *(const double2*)&Bs[(tx + 32) * 34 + k];
      double2 C3 = *(const double2*)&Bs[(tx + 48) * 34 + k];
      FMA16D(A0.x, A1.x, A2.x, A3.x, C0.x, C1.x, C2.x, C3.x)  // k
      FMA16D(A0.y, A1.y, A2.y, A3.y, C0.y, C1.y, C2.y, C3.y)  // k+1
    }
  }
  __syncthreads();  // As/Bs dead from here; Ls/Ss may overwrite
  double Lmax = __longlong_as_double((long long)(*lmaxp));
  bool diag = (I == J);
#pragma unroll
  for (int p = 0; p < 4; ++p) {
    int r = ty + 16 * p;
    int gi = I * 64 + r;
    u64 wO = bitO[(size_t)gi * NW + J];  // directed bits, row gi, col-block J
    float sv[4];
#pragma unroll
    for (int q = 0; q < 4; ++q) {
      int c = tx + 16 * q;
      int gj = J * 64 + c;
      double L = acc[p][q];
      float lf = (float)L;
      adjL[(size_t)gi * NN + gj] = lf;
      adjO[(size_t)gi * NN + gj] = (float)((wO >> c) & 1ull);
      float stv;
      if (diag && r == c) {
        stv = 1.0f;  // fill_diagonal_(1)
      } else {
        // only the upper-triangle (a<b) entry decides; L[a,b]==L[b,a] bitwise
        int ga = gi < gj ? gi : gj, gb = gi < gj ? gj : gi;
        size_t ab = (size_t)ga * NN + gb;
        double uu = (double)u[ab];
        double ao = (double)(int)((bitO[(size_t)ga * NW + (gb >> 6)] >> (gb & 63)) & 1ull);
        double ep = 0.8 * (L / Lmax) + 0.2 * ao;
        if (ep < 0.0) ep = 0.0;
        double pl = ep;
        if (pl < 1e-6) pl = 1e-6;
        double hi = 1.0 - 1e-6;
        if (pl > hi) pl = hi;
        stv = (pl > 1.0 - uu) ? 1.0f : 0.0f;  // == round(sigmoid(logit(pl)+logit(uu)))
      }
      sv[q] = stv;
      adjS[(size_t)gi * NN + gj] = stv;
      if (!diag) {
        Ls[c * 68 + r] = lf;   // store transposed for mirror tile
        Ss[c * 68 + r] = stv;
      }
    }
    // pack this row's 64 sample bits: wave lane l = (ty&3)*16+tx holds (row ty+16p, col tx+16q)
    u64 word = 0;
#pragma unroll
    for (int q = 0; q < 4; ++q) {
      u64 m = __ballot(sv[q] > 0.5f);
      word |= ((m >> ((ty & 3) * 16)) & 0xFFFFull) << (16 * q);
    }
    if (tx == 0) bitT[(size_t)J * NN + gi] = word;  // transposed: [col-block][row]
  }
  if (!diag) {
    __syncthreads();
    // mirror float tiles, float4-vectorized (stride 68*4 B = 272 -> 16B aligned rows)
    for (int i4 = t; i4 < 1024; i4 += 256) {
      int a = i4 >> 4, b4 = (i4 & 15) << 2;
      int grow = J * 64 + a;
      size_t off = (size_t)grow * NN + (I * 64 + b4);
      *(float4*)(adjL + off) = *(const float4*)&Ls[a * 68 + b4];
      *(float4*)(adjS + off) = *(const float4*)&Ss[a * 68 + b4];
      u64 wOm = bitO[(size_t)grow * NW + I];  // directed bits row grow, col-block I
      *(float4*)(adjO + off) = make_float4((float)((wOm >> b4) & 1ull),
                                           (float)((wOm >> (b4 + 1)) & 1ull),
                                           (float)((wOm >> (b4 + 2)) & 1ull),
                                           (float)((wOm >> (b4 + 3)) & 1ull));
    }
    // mirror bits: per wave-iteration all 64 lanes hold one row (a = 4*k2 + wave), col = lane
    for (int k2 = 0; k2 < 16; ++k2) {
      int idx = t + (k2 << 8);
      int a = idx >> 6, b = idx & 63;
      u64 m = __ballot(Ss[a * 68 + b] > 0.5f);
      if ((t & 63) == 0) bitT[(size_t)I * NN + (J * 64 + a)] = m;
    }
  }
}

// ---------- row sums of adj_sampled via popcount (transposed layout: coalesced) ----------
__global__ __launch_bounds__(256) void k_rowsumB(const u64* __restrict__ bitT,
                                                 double* __restrict__ dinv2) {
  int i = blockIdx.x * 256 + threadIdx.x;
  int cnt = 0;
#pragma unroll
  for (int J = 0; J < NW; ++J) cnt += __popcll(bitT[(size_t)J * NN + i]);
  dinv2[i] = 1.0 / sqrt((double)(cnt + 1));
}

// ---------- g[j,c] = dinv2[j] * hxw[j,c] (fp32 for the continuous path) ----------
__global__ __launch_bounds__(256) void k_gscale(const double* __restrict__ hv,
                                                const double* __restrict__ dinv2,
                                                float* __restrict__ g) {
  int t = blockIdx.x * 256 + threadIdx.x;
  int j = t >> 6;
  g[t] = (float)(dinv2[j] * hv[t]);
}

// 8 packed (2-wide) fp32 fmas for one j-substep: 16 scalar fmas as v_pk_fma_f32.
// Each half of a v2f fma is an independent IEEE fma -> every acc element keeps its own
// j-ascending chain with identical values -> bitwise identical to the scalar version.
#define FMA8P(B0, B1, B2, B3, CVA, CVB)                                          \
  acc[0][0] = __builtin_elementwise_fma(B0, CVA, acc[0][0]);                     \
  acc[0][1] = __builtin_elementwise_fma(B0, CVB, acc[0][1]);                     \
  acc[1][0] = __builtin_elementwise_fma(B1, CVA, acc[1][0]);                     \
  acc[1][1] = __builtin_elementwise_fma(B1, CVB, acc[1][1]);                     \
  acc[2][0] = __builtin_elementwise_fma(B2, CVA, acc[2][0]);                     \
  acc[2][1] = __builtin_elementwise_fma(B2, CVB, acc[2][1]);                     \
  acc[3][0] = __builtin_elementwise_fma(B3, CVA, acc[3][0]);                     \
  acc[3][1] = __builtin_elementwise_fma(B3, CVB, acc[3][1]);

// ---------- dense An-matmul partial: slice s sums j in [s*768, (s+1)*768) ----------
// vs the 1033 us build, ONE change: the 16 scalar fmas per j are packed into 8 two-wide
// vector fmas (ext_vector float2 + __builtin_elementwise_fma -> llvm.fma.v2f32 ->
// v_pk_fma_f32 on gfx950). VALU instrs per j drop 24 -> 16 (8 pk_fma + 4 bfe + 4 cvt),
// removing the ~50% VALU overhead over the fma floor. Bit extraction (32-bit halves,
// compile-time shifts) and the per-element fma chains (j asc, Jt asc, same split-K)
// are unchanged -> bitwise-identical accumulators, absmax unchanged.
__global__ __launch_bounds__(256) void k_anmm(const u64* __restrict__ bitT,
                                              const float* __restrict__ g,
                                              float* __restrict__ accb) {
  int I = blockIdx.x;  // 0..95 row block
  int s = blockIdx.y;  // 0..7 split-K slice
  __shared__ __align__(16) float gs[64 * 64];  // 16,384 B
  int t = threadIdx.x, tx = t & 15, ty = t >> 4;
  v2f acc[4][2];
#pragma unroll
  for (int p = 0; p < 4; ++p) {
    acc[p][0] = (v2f)(0.0f);
    acc[p][1] = (v2f)(0.0f);
  }
  for (int Jt = s * 12; Jt < (s + 1) * 12; ++Jt) {
    // issue the 4 broadcast row-word loads first: latency overlaps gs staging + barrier
    const u64* bw = bitT + (size_t)Jt * NN + I * 64;
    u64 w0 = bw[ty];        // 16 lanes share each word, L2-resident
    u64 w1 = bw[ty + 16];
    u64 w2 = bw[ty + 32];
    u64 w3 = bw[ty + 48];
    __syncthreads();
    for (int i4 = t; i4 < 1024; i4 += 256) {
      int r = i4 >> 4, c4 = (i4 & 15) << 2;
      *(float4*)&gs[r * 64 + c4] = *(const float4*)&g[(size_t)(Jt * 64 + r) * HID + c4];
    }
    __syncthreads();
    unsigned lo0 = (unsigned)w0, hi0 = (unsigned)(w0 >> 32);
    unsigned lo1 = (unsigned)w1, hi1 = (unsigned)(w1 >> 32);
    unsigned lo2 = (unsigned)w2, hi2 = (unsigned)(w2 >> 32);
    unsigned lo3 = (unsigned)w3, hi3 = (unsigned)(w3 >> 32);
    const float* gp = gs + (tx << 2);
#pragma unroll 8
    for (int j = 0; j < 32; ++j) {   // j ascending: identical fma order
      float4 cv = *(const float4*)&gp[j * 64];
      v2f cva = {cv.x, cv.y}, cvb = {cv.z, cv.w};
      float b0 = (float)((lo0 >> j) & 1u);
      float b1 = (float)((lo1 >> j) & 1u);
      float b2 = (float)((lo2 >> j) & 1u);
      float b3 = (float)((lo3 >> j) & 1u);
      v2f B0 = {b0, b0}, B1 = {b1, b1}, B2 = {b2, b2}, B3 = {b3, b3};
      FMA8P(B0, B1, B2, B3, cva, cvb)
    }
#pragma unroll 8
    for (int j = 0; j < 32; ++j) {   // j+32, ascending
      float4 cv = *(const float4*)&gp[(j + 32) * 64];
      v2f cva = {cv.x, cv.y}, cvb = {cv.z, cv.w};
      float b0 = (float)((hi0 >> j) & 1u);
      float b1 = (float)((hi1 >> j) & 1u);
      float b2 = (float)((hi2 >> j) & 1u);
      float b3 = (float)((hi3 >> j) & 1u);
      v2f B0 = {b0, b0}, B1 = {b1, b1}, B2 = {b2, b2}, B3 = {b3, b3};
      FMA8P(B0, B1, B2, B3, cva, cvb)
    }
  }
  float* out = accb + (size_t)s * NN * HID;
#pragma unroll
  for (int p = 0; p < 4; ++p) {
    float4 v = make_float4(acc[p][0].x, acc[p][0].y, acc[p][1].x, acc[p][1].y);
    *(float4*)&out[(size_t)(I * 64 + ty + 16 * p) * HID + (tx << 2)] = v;
  }
}

// ---------- epilogue 1: x1 = dinv2_i*(sum + g_i) + b1; z = PReLU(x1) ----------
__global__ __launch_bounds__(256) void k_ep1(const float* __restrict__ accb,
                                             const float* __restrict__ g,
                                             const double* __restrict__ dinv2,
                                             const float* __restrict__ b1,
                                             const float* __restrict__ prelu,
                                             float* __restrict__ x1,
                                             float* __restrict__ zout) {
  int t = blockIdx.x * 256 + threadIdx.x;
  int i = t >> 6, c = t & 63;
  double ss = 0.0;
  for (int s = 0; s < 8; ++s) ss += (double)accb[(size_t)s * NN * HID + t];
  float v = (float)(dinv2[i] * (ss + (double)g[t])) + b1[c];
  x1[t] = v;
  float pa = prelu[0];
  zout[t] = v >= 0.0f ? v : pa * v;
}

// ---------- BN stats (biased var, training mode) ----------
__global__ __launch_bounds__(256) void k_bnstats(const float* __restrict__ x1,
                                                 double* __restrict__ meanv,
                                                 double* __restrict__ istd) {
  __shared__ double r1[256], r2[256];
  int c = blockIdx.x;
  double s1 = 0.0, s2 = 0.0;
  for (int i = threadIdx.x; i < NN; i += 256) {
    double v = (double)x1[(size_t)i * HID + c];
    s1 += v;
    s2 += v * v;
  }
  r1[threadIdx.x] = s1;
  r2[threadIdx.x] = s2;
  __syncthreads();
  for (int w = 128; w > 0; w >>= 1) {
    if (threadIdx.x < w) {
      r1[threadIdx.x] += r1[threadIdx.x + w];
      r2[threadIdx.x] += r2[threadIdx.x + w];
    }
    __syncthreads();
  }
  if (threadIdx.x == 0) {
    double m = r1[0] / (double)NN;
    double var = r2[0] / (double)NN - m * m;
    meanv[c] = m;
    istd[c] = 1.0 / sqrt(var + 1e-5);
  }
}

// ---------- fused BN-apply + ReLU + (xr @ W2) + dinv2 scale ----------
__global__ __launch_bounds__(256) void k_xryg2(const float* __restrict__ x1,
                                               const double* __restrict__ meanv,
                                               const double* __restrict__ istd,
                                               const float* __restrict__ gamma,
                                               const float* __restrict__ beta,
                                               const float* __restrict__ W2,
                                               const double* __restrict__ dinv2,
                                               float* __restrict__ g2) {
  __shared__ float xs[4 * 64];
  int t = threadIdx.x;
  int t2 = blockIdx.x * 256 + t;
  int c = t & 63;
  float v = gamma[c] * (float)(((double)x1[t2] - meanv[c]) * istd[c]) + beta[c];
  xs[t] = v > 0.0f ? v : 0.0f;
  __syncthreads();
  const float* xrow = xs + (t >> 6) * 64;
  float a = 0.0f;
#pragma unroll 8
  for (int k = 0; k < HID; ++k) a = fmaf(xrow[k], W2[k * HID + c], a);
  int j = t2 >> 6;
  g2[t2] = (float)(dinv2[j] * (double)a);
}

// ---------- epilogue 2: x2 = dinv2_i*(sum + g2_i) + b2 ----------
__global__ __launch_bounds__(256) void k_ep2(const float* __restrict__ accb,
                                             const float* __restrict__ g2,
                                             const double* __restrict__ dinv2,
                                             const float* __restrict__ b2p,
                                             float* __restrict__ x2out) {
  int t = blockIdx.x * 256 + threadIdx.x;
  int i = t >> 6, c = t & 63;
  double ss = 0.0;
  for (int s = 0; s < 8; ++s) ss += (double)accb[(size_t)s * NN * HID + t];
  x2out[t] = (float)(dinv2[i] * (ss + (double)g2[t])) + b2p[c];
}

extern "C" void kernel_launch(void* const* d_in, const int* in_sizes, int n_in,
                              void* d_out, int out_size, void* d_ws, size_t ws_size,
                              hipStream_t stream) {
  const float* x = (const float*)d_in[0];
  const int* ei = (const int*)d_in[1];
  const float* W1 = (const float*)d_in[2];
  const float* b1 = (const float*)d_in[3];
  const float* W2 = (const float*)d_in[4];
  const float* b2 = (const float*)d_in[5];
  const float* gamma = (const float*)d_in[6];
  const float* beta = (const float*)d_in[7];
  const float* prelu = (const float*)d_in[8];
  const float* u = (const float*)d_in[9];
  int E = in_sizes[1] / 2;

  float* out = (float*)d_out;
  float* o_x2 = out;
  float* o_z = out + (size_t)NN * HID;
  float* o_adjS = out + (size_t)2 * NN * HID;
  float* o_adjL = o_adjS + (size_t)NN * NN;
  float* o_adjO = o_adjL + (size_t)NN * NN;

  // workspace layout: region A (phase-1, later overlaid by accb), region B persistent.
  // bitO (4,718,592 B) overlays x1/gg: bitO lifetime ends at k_tile; x1/gg are first
  // written after k_tile. bitT (transposed sample bits) is appended.
  char* w = (char*)d_ws;
  double* hxw = (double*)w;                        // 3,145,728 B
  double* hagg = (double*)(w + 3145728);           // 3,145,728 B
  double* dinv = (double*)(w + 6291456);           // 49,152 B
  int* deg = (int*)(w + 6340608);                  // 24,576 B
  float* accb = (float*)w;                         // 12,582,912 B, overlays dead region A
  double* dinv2 = (double*)(w + 12582912);         // 49,152 B
  u64* lmax = (u64*)(w + 12632064);                // 8 B
  double* meanv = (double*)(w + 12632128);         // 512 B
  double* istd = (double*)(w + 12632640);          // 512 B
  float* x1 = (float*)(w + 12633152);              // 1,572,864 B
  float* gg = (float*)(w + 14206016);              // 1,572,864 B
  float* g2 = (float*)(w + 17351744);              // 1,572,864 B
  u64* bitO = (u64*)(w + 12633152);                // 4,718,592 B, overlays x1/gg
  u64* bitT = (u64*)(w + 18924608);                // 4,718,592 B -> total 23,643,200 B

  hipMemsetAsync(deg, 0, NN * sizeof(int), stream);
  hipMemsetAsync(hagg, 0, (size_t)NN * HID * sizeof(double), stream);
  hipMemsetAsync(lmax, 0, sizeof(u64), stream);
  hipMemsetAsync(bitO, 0, (size_t)NN * NW * sizeof(u64), stream);

  k_hxw<<<NN * HID / 256, 256, 0, stream>>>(x, W1, hxw);
  k_edges<<<(E + 255) / 256, 256, 0, stream>>>(ei, E, deg, bitO);
  k_dinv<<<NN / 256, 256, 0, stream>>>(deg, dinv);
  k_agg<<<(E * HID + 255) / 256, 256, 0, stream>>>(ei, E, hxw, dinv, hagg);
  k_selfbias<<<NN * HID / 256, 256, 0, stream>>>(hxw, dinv, b1, hagg);
  k_lmax<<<NN / 256, 256, 0, stream>>>(hagg, lmax);
  dim3 gt(96, 96);
  k_tile<<<gt, 256, 0, stream>>>(hagg, lmax, u, bitO, o_adjL, o_adjS, o_adjO, bitT);
  k_rowsumB<<<NN / 256, 256, 0, stream>>>(bitT, dinv2);
  k_gscale<<<NN * HID / 256, 256, 0, stream>>>(hxw, dinv2, gg);
  dim3 ga(96, 8);
  k_anmm<<<ga, 256, 0, stream>>>(bitT, gg, accb);
  k_ep1<<<NN * HID / 256, 256, 0, stream>>>(accb, gg, dinv2, b1, prelu, x1, o_z);
  k_bnstats<<<HID, 256, 0, stream>>>(x1, meanv, istd);
  k_xryg2<<<NN * HID / 256, 256, 0, stream>>>(x1, meanv, istd, gamma, beta, W2, dinv2, g2);
  k_anmm<<<ga, 256, 0, stream>>>(bitT, g2, accb);
  k_ep2<<<NN * HID / 256, 256, 0, stream>>>(accb, g2, dinv2, b2, o_x2);
}